// Round 22
// baseline (396.599 us; speedup 1.0000x reference)
//
#include <hip/hip_runtime.h>
#include <math.h>

#define D_ 128
#define NH_ 8
#define G_ 2048
#define B_ 4
#define KEEP_ 512
#define NENC_ 513
#define HID_ 512
#define EPS_ 1e-5f

typedef short bf16x8 __attribute__((ext_vector_type(8)));
typedef short s16x4 __attribute__((ext_vector_type(4)));
typedef float f32x4 __attribute__((ext_vector_type(4)));
typedef unsigned u32x4 __attribute__((ext_vector_type(4)));

static __device__ __forceinline__ float b2f(short s) {
    union { float f; unsigned u; } v;
    v.u = ((unsigned)(unsigned short)s) << 16;
    return v.f;
}
static __device__ __forceinline__ short f2b(float f) {
    union { float f; unsigned u; } v;
    v.f = f;
    unsigned r = v.u + 0x7fffu + ((v.u >> 16) & 1u);   // RNE
    return (short)(r >> 16);
}
static __device__ __forceinline__ unsigned cvtpk(float lo, float hi) {
    unsigned r;
    asm("v_cvt_pk_bf16_f32 %0, %1, %2" : "=v"(r) : "v"(lo), "v"(hi));
    return r;
}
static __device__ __forceinline__ float fexp2(float x) {   // 2^x, 1 instr
    float r;
    asm("v_exp_f32 %0, %1" : "=v"(r) : "v"(x));
    return r;
}
static __device__ __forceinline__ float gelu_f(float v) {  // tanh-gelu via exp2
    float u = v * (0.7978845608f + 0.0356774081f * v * v);
    float t = fexp2(fminf(u * 2.8853900818f, 80.f));
    return v * t / (t + 1.0f);
}

#define QSCALE_LOG2 0.3606737602f   /* 0.25 * log2(e) */
#define X16(r) ((((r) >> 1) & 7) << 4)

// ---------------------------------------------------------------------------
// Stable rank. 1024 threads: 4 threads per i, 4 independent accumulator chains.
// ---------------------------------------------------------------------------
__global__ __launch_bounds__(1024) void rank_kernel(
    const float* __restrict__ noise, int* __restrict__ rank,
    int* __restrict__ keep_ids, float* __restrict__ mask_out) {
    int b = blockIdx.y;
    int tid = threadIdx.x;
    int li = tid & 255;
    int chunk = tid >> 8;
    int i = blockIdx.x * 256 + li;
    __shared__ float sn[G_];
    __shared__ int pr[1024];
    const float* row = noise + (size_t)b * G_;
    for (int j = tid; j < G_; j += 1024) sn[j] = row[j];
    __syncthreads();
    float vi = sn[i];
    int j0 = chunk * 512;
    int r0 = 0, r1 = 0, r2 = 0, r3 = 0;
    #pragma unroll 4
    for (int j = j0; j < j0 + 512; j += 4) {
        float a0 = sn[j], a1 = sn[j + 1], a2 = sn[j + 2], a3 = sn[j + 3];
        r0 += (a0 < vi) || (a0 == vi && (j + 0) < i);
        r1 += (a1 < vi) || (a1 == vi && (j + 1) < i);
        r2 += (a2 < vi) || (a2 == vi && (j + 2) < i);
        r3 += (a3 < vi) || (a3 == vi && (j + 3) < i);
    }
    pr[tid] = r0 + r1 + r2 + r3;
    __syncthreads();
    if (tid < 256) {
        int r = pr[tid] + pr[tid + 256] + pr[tid + 512] + pr[tid + 768];
        rank[b * G_ + i] = r;
        mask_out[b * G_ + i] = (r >= KEEP_) ? 1.0f : 0.0f;
        if (r < KEEP_) keep_ids[b * KEEP_ + r] = i;
    }
}

// ---------------------------------------------------------------------------
__global__ void prep_kernel(
    const float* __restrict__ eqkvw, const float* __restrict__ eprjw,
    const float* __restrict__ ef1w,  const float* __restrict__ ef2w,
    const float* __restrict__ dqkvw, const float* __restrict__ dprjw,
    const float* __restrict__ df1w,  const float* __restrict__ df2w,
    const float* __restrict__ dew,
    short* eqkvT, short* eprjT, short* ef1T, short* ef2T,
    short* dqkvT, short* dprjT, short* df1T, short* df2T, short* dembT) {
    int z = blockIdx.z;
    const float* s; short* d; int K, N;
    if (z < 6)       { int l = z;      s = eqkvw + (size_t)l * 128 * 384; d = eqkvT + (size_t)l * 384 * 128; K = 128; N = 384; }
    else if (z < 12) { int l = z - 6;  s = eprjw + (size_t)l * 128 * 128; d = eprjT + (size_t)l * 128 * 128; K = 128; N = 128; }
    else if (z < 18) { int l = z - 12; s = ef1w  + (size_t)l * 128 * 512; d = ef1T  + (size_t)l * 512 * 128; K = 128; N = 512; }
    else if (z < 24) { int l = z - 18; s = ef2w  + (size_t)l * 512 * 128; d = ef2T  + (size_t)l * 128 * 512; K = 512; N = 128; }
    else if (z < 26) { int l = z - 24; s = dqkvw + (size_t)l * 128 * 384; d = dqkvT + (size_t)l * 384 * 128; K = 128; N = 384; }
    else if (z < 28) { int l = z - 26; s = dprjw + (size_t)l * 128 * 128; d = dprjT + (size_t)l * 128 * 128; K = 128; N = 128; }
    else if (z < 30) { int l = z - 28; s = df1w  + (size_t)l * 128 * 512; d = df1T  + (size_t)l * 512 * 128; K = 128; N = 512; }
    else if (z < 32) { int l = z - 30; s = df2w  + (size_t)l * 512 * 128; d = df2T  + (size_t)l * 128 * 512; K = 512; N = 128; }
    else             { s = dew; d = dembT; K = 128; N = 128; }
    int n0 = blockIdx.x * 32, k0 = blockIdx.y * 32;
    if (n0 >= N || k0 >= K) return;
    __shared__ float t[32][33];
    int tx = threadIdx.x & 31, ty = threadIdx.x >> 5;
    #pragma unroll
    for (int i = 0; i < 32; i += 8)
        t[ty + i][tx] = s[(size_t)(k0 + ty + i) * N + n0 + tx];
    __syncthreads();
    #pragma unroll
    for (int i = 0; i < 32; i += 8)
        d[(size_t)(n0 + ty + i) * K + k0 + tx] = f2b(t[tx][ty + i]);
}

// ---------------------------------------------------------------------------
static __device__ __forceinline__ float row_ln_128(float v, int t, const float* g,
                                                   const float* bta, float* ss, float* qq) {
    float s = v;
    #pragma unroll
    for (int o = 1; o < 64; o <<= 1) s += __shfl_xor(s, o);
    if ((t & 63) == 0) ss[t >> 6] = s;
    __syncthreads();
    float mu = (ss[0] + ss[1]) * (1.0f / D_);
    float dv = v - mu;
    float q = dv * dv;
    #pragma unroll
    for (int o = 1; o < 64; o <<= 1) q += __shfl_xor(q, o);
    if ((t & 63) == 0) qq[t >> 6] = q;
    __syncthreads();
    float var = (qq[0] + qq[1]) * (1.0f / D_);
    return dv * rsqrtf(var + EPS_) * g[t] + bta[t];
}

// ---------------------------------------------------------------------------
__global__ void embed_ln_kernel(const float* __restrict__ x, const float* __restrict__ pos,
                                const float* __restrict__ cls, const float* __restrict__ ew,
                                const float* __restrict__ eb, const int* __restrict__ keep_ids,
                                const float* __restrict__ lnw, const float* __restrict__ lnb,
                                float* __restrict__ resid, short* __restrict__ lout) {
    int n = blockIdx.x, b = blockIdx.y;
    int t = threadIdx.x;
    float v;
    if (n == 0) v = cls[t];
    else {
        int i = keep_ids[b * KEEP_ + (n - 1)];
        v = x[b * G_ + i] * ew[t] + eb[t] + pos[(size_t)i * D_ + t];
    }
    size_t row = (size_t)b * NENC_ + n;
    resid[row * D_ + t] = v;
    __shared__ float ss[2], qq[2];
    lout[row * D_ + t] = f2b(row_ln_128(v, t, lnw, lnb, ss, qq));
}

// ---------------------------------------------------------------------------
__global__ void decbuild_ln_kernel(const float* __restrict__ dembed, const float* __restrict__ mask_token,
                                   const float* __restrict__ pos, const int* __restrict__ rank,
                                   const float* __restrict__ lnw, const float* __restrict__ lnb,
                                   float* __restrict__ resid, short* __restrict__ lout) {
    int i = blockIdx.x, b = blockIdx.y;
    int t = threadIdx.x;
    int r = rank[b * G_ + i];
    float v = (r < KEEP_) ? dembed[((size_t)b * NENC_ + 1 + r) * D_ + t] : mask_token[t];
    v += pos[(size_t)i * D_ + t];
    size_t row = (size_t)b * G_ + i;
    resid[row * D_ + t] = v;
    __shared__ float ss[2], qq[2];
    lout[row * D_ + t] = f2b(row_ln_128(v, t, lnw, lnb, ss, qq));
}

// ---------------------------------------------------------------------------
// bf16 MFMA GEMM, BM-row M-tile (32/64/128) x 128-col N-tile, BK=64.
// MODE 0: fp32 out   MODE 3: bf16 out (Q cols ×0.25*log2e when blockIdx.y==0)
// ---------------------------------------------------------------------------
template<int MODE, int BM>
__global__ __launch_bounds__(256) void gemm_mfma_kernel(
    const short* __restrict__ A, const short* __restrict__ Wt,
    const float* __restrict__ bias, void* __restrict__ Cout, int M, int K, int N) {
    constexpr int AM_ = (BM + 31) / 32;
    constexpr int RW = BM / 2;
    __shared__ short As[BM * 64];
    __shared__ short Bs[128 * 64];
    int tid = threadIdx.x;
    int lane = tid & 63, wid = tid >> 6;
    int wr = wid >> 1, wc = wid & 1;
    int bm = blockIdx.x * BM, bn = blockIdx.y * 128;
    int l15 = lane & 15, lhi = lane >> 4;
    f32x4 acc[AM_][4];
    #pragma unroll
    for (int m = 0; m < AM_; ++m)
        #pragma unroll
        for (int n = 0; n < 4; ++n) acc[m][n] = f32x4{0.f, 0.f, 0.f, 0.f};

    const char* Ab = (const char*)A;
    const char* Bb = (const char*)Wt;
    char* AsB = (char*)As;
    char* BsB = (char*)Bs;
    int p = tid * 16;
    int r0 = p >> 7, cb0 = p & 127;

    for (int k0 = 0; k0 < K; k0 += 64) {
        __syncthreads();
        #pragma unroll
        for (int it = 0; it < BM / 32; ++it) {
            int r = r0 + it * 32;
            int scb = cb0 ^ ((r & 7) << 4);
            __builtin_amdgcn_global_load_lds(
                (const __attribute__((address_space(1))) void*)(Ab + (((size_t)(bm + r) * K + k0) << 1) + scb),
                (__attribute__((address_space(3))) void*)(AsB + it * 4096 + (wid << 10)), 16, 0, 0);
        }
        #pragma unroll
        for (int it = 0; it < 4; ++it) {
            int r = r0 + it * 32;
            int scb = cb0 ^ ((r & 7) << 4);
            __builtin_amdgcn_global_load_lds(
                (const __attribute__((address_space(1))) void*)(Bb + (((size_t)(bn + r) * K + k0) << 1) + scb),
                (__attribute__((address_space(3))) void*)(BsB + it * 4096 + (wid << 10)), 16, 0, 0);
        }
        asm volatile("s_waitcnt vmcnt(0)" ::: "memory");
        __syncthreads();
        #pragma unroll
        for (int kk = 0; kk < 2; ++kk) {
            bf16x8 a[AM_], b[4];
            int cbb = kk * 64 + lhi * 16;
            #pragma unroll
            for (int m = 0; m < AM_; ++m) {
                int row = wr * RW + m * 16 + l15;
                a[m] = *(const bf16x8*)(AsB + row * 128 + (cbb ^ ((row & 7) << 4)));
            }
            #pragma unroll
            for (int m = 0; m < 4; ++m) {
                int rowb = wc * 64 + m * 16 + l15;
                b[m] = *(const bf16x8*)(BsB + rowb * 128 + (cbb ^ ((rowb & 7) << 4)));
            }
            #pragma unroll
            for (int m = 0; m < AM_; ++m)
                #pragma unroll
                for (int n = 0; n < 4; ++n)
                    acc[m][n] = __builtin_amdgcn_mfma_f32_16x16x32_bf16(a[m], b[n], acc[m][n], 0, 0, 0);
        }
    }

    float qsc = (MODE == 3 && blockIdx.y == 0) ? QSCALE_LOG2 : 1.0f;
    #pragma unroll
    for (int m = 0; m < AM_; ++m) {
        int rbase = bm + wr * RW + m * 16 + lhi * 4;
        #pragma unroll
        for (int n = 0; n < 4; ++n) {
            int col = bn + wc * 64 + n * 16 + l15;
            float bv = bias[col];
            #pragma unroll
            for (int j = 0; j < 4; ++j) {
                int rr = rbase + j;
                if (rr < M) {
                    float v = acc[m][n][j] + bv;
                    if (MODE == 3) ((short*)Cout)[(size_t)rr * N + col] = f2b(v * qsc);
                    else           ((float*)Cout)[(size_t)rr * N + col] = v;
                }
            }
        }
    }
}

// ---------------------------------------------------------------------------
// Mega layer-tail kernel with FUSED attn-combine A-staging:
// combine(accp,mlp) -> A-tile -> proj + resid + LN2 + fc1 + GELU + fc2 + resid + LN.
// MT = 32 (72KB LDS).  FIN 0: resid+LN  FIN 1: +cls  FIN 2: loss
// ---------------------------------------------------------------------------
template<int FIN, int MT>
__global__ __launch_bounds__(256) void mega_mlp_kernel(
    const float* __restrict__ accpp, const float* __restrict__ mlpp, int rowsTot,
    const short* __restrict__ prjT,
    const float* __restrict__ prjb, float* __restrict__ resid,
    const short* __restrict__ W1t, const float* __restrict__ b1,
    const short* __restrict__ W2t, const float* __restrict__ b2,
    const float* __restrict__ ln2w, const float* __restrict__ ln2b,
    const float* __restrict__ lnfw, const float* __restrict__ lnfb,
    short* __restrict__ Lout,
    const float* __restrict__ pwv, const float* __restrict__ pbv,
    const float* __restrict__ xin, const int* __restrict__ rankp,
    float* __restrict__ predp, float* __restrict__ bsumsp, int M) {
    constexpr int M_ = MT / 32;
    constexpr int RW = MT / 2;
    __shared__ short As[MT * 128];
    __shared__ short Bs[128 * 128];
    __shared__ short GL[MT * 512];
    char* AsB = (char*)As;
    char* BsB = (char*)Bs;
    char* GLB = (char*)GL;
    int tid = threadIdx.x;
    int lane = tid & 63, wid = tid >> 6;
    int wr = wid >> 1, wc = wid & 1;
    int l15 = lane & 15, lhi = lane >> 4;
    int bm = blockIdx.x * MT;
    int r0 = tid >> 4, cb0 = (tid & 15) << 4;

#define MSTAGE(SRCB, RSTRIDE, DST, ITERS) do {                                     \
        _Pragma("unroll")                                                          \
        for (int it = 0; it < (ITERS); ++it) {                                     \
            int r = r0 + it * 16;                                                  \
            int scb = cb0 ^ X16(r);                                                \
            __builtin_amdgcn_global_load_lds(                                      \
                (const __attribute__((address_space(1))) void*)((SRCB) + (size_t)r * (RSTRIDE) + scb), \
                (__attribute__((address_space(3))) void*)((DST) + it * 4096 + (tid << 4)), 16, 0, 0); \
        }                                                                          \
    } while (0)

    // ---- phase 0: fused attn-combine -> A-tile (ds_write), B via gload_lds ----
    #pragma unroll
    for (int it = 0; it < MT / 16; ++it) {
        int r = r0 + it * 16;
        int gr = bm + r; gr = gr < M ? gr : M - 1;
        int cg = (cb0 ^ X16(r)) >> 1;              // elem col (8-aligned, one head)
        int h = cg >> 4;
        const float* ml0 = mlpp + (size_t)gr * 16 + h * 2;
        const float* ml1 = ml0 + (size_t)rowsTot * 16;
        float m0 = ml0[0], l0 = ml0[1];
        float m1 = ml1[0], l1 = ml1[1];
        float M2 = fmaxf(m0, m1);
        float w0 = fexp2(m0 - M2), w1 = fexp2(m1 - M2);
        float rd = 1.0f / (w0 * l0 + w1 * l1);
        w0 *= rd; w1 *= rd;
        const float* a0p = accpp + (size_t)gr * 128 + cg;
        const float* a1p = a0p + (size_t)rowsTot * 128;
        f32x4 a0 = *(const f32x4*)a0p;
        f32x4 a0b = *(const f32x4*)(a0p + 4);
        f32x4 a1 = *(const f32x4*)a1p;
        f32x4 a1b = *(const f32x4*)(a1p + 4);
        u32x4 w;
        w[0] = cvtpk(w0 * a0[0] + w1 * a1[0], w0 * a0[1] + w1 * a1[1]);
        w[1] = cvtpk(w0 * a0[2] + w1 * a1[2], w0 * a0[3] + w1 * a1[3]);
        w[2] = cvtpk(w0 * a0b[0] + w1 * a1b[0], w0 * a0b[1] + w1 * a1b[1]);
        w[3] = cvtpk(w0 * a0b[2] + w1 * a1b[2], w0 * a0b[3] + w1 * a1b[3]);
        *(u32x4*)(AsB + it * 4096 + (tid << 4)) = w;
    }
    MSTAGE((const char*)prjT, 256, BsB, 8);
    asm volatile("s_waitcnt vmcnt(0)" ::: "memory");
    __syncthreads();
    f32x4 acc0[M_][4];
    #pragma unroll
    for (int m = 0; m < M_; ++m)
        #pragma unroll
        for (int n = 0; n < 4; ++n) acc0[m][n] = f32x4{0.f, 0.f, 0.f, 0.f};
    #pragma unroll
    for (int kk = 0; kk < 4; ++kk) {
        bf16x8 a[M_], b[4];
        int cb = kk * 64 + lhi * 16;
        #pragma unroll
        for (int m = 0; m < M_; ++m) {
            int row = wr * RW + m * 16 + l15;
            a[m] = *(const bf16x8*)(AsB + row * 256 + (cb ^ X16(row)));
        }
        #pragma unroll
        for (int n = 0; n < 4; ++n) {
            int rb = wc * 64 + n * 16 + l15;
            b[n] = *(const bf16x8*)(BsB + rb * 256 + (cb ^ X16(rb)));
        }
        #pragma unroll
        for (int m = 0; m < M_; ++m)
            #pragma unroll
            for (int n = 0; n < 4; ++n)
                acc0[m][n] = __builtin_amdgcn_mfma_f32_16x16x32_bf16(a[m], b[n], acc0[m][n], 0, 0, 0);
    }
    #pragma unroll
    for (int m = 0; m < M_; ++m)
        #pragma unroll
        for (int n = 0; n < 4; ++n) {
            int col = wc * 64 + n * 16 + l15;
            float bv = prjb[col];
            #pragma unroll
            for (int j = 0; j < 4; ++j) {
                int rr = bm + wr * RW + m * 16 + lhi * 4 + j;
                int rc = rr < M ? rr : M - 1;
                acc0[m][n][j] += bv + resid[(size_t)rc * 128 + col];
            }
        }
    float* sst = (float*)GL;
    #pragma unroll
    for (int m = 0; m < M_; ++m)
        #pragma unroll
        for (int j = 0; j < 4; ++j) {
            float ps = 0.f, pq = 0.f;
            #pragma unroll
            for (int n = 0; n < 4; ++n) { float t0 = acc0[m][n][j]; ps += t0; pq += t0 * t0; }
            #pragma unroll
            for (int o = 1; o < 16; o <<= 1) { ps += __shfl_xor(ps, o); pq += __shfl_xor(pq, o); }
            if (l15 == 0) {
                int row = wr * RW + m * 16 + lhi * 4 + j;
                sst[row * 4 + wc * 2 + 0] = ps;
                sst[row * 4 + wc * 2 + 1] = pq;
            }
        }
    __syncthreads();
    #pragma unroll
    for (int m = 0; m < M_; ++m)
        #pragma unroll
        for (int j = 0; j < 4; ++j) {
            int row = wr * RW + m * 16 + lhi * 4 + j;
            float s0 = sst[row * 4 + 0] + sst[row * 4 + 2];
            float q0 = sst[row * 4 + 1] + sst[row * 4 + 3];
            float mu = s0 * (1.0f / 128.0f);
            float var = q0 * (1.0f / 128.0f) - mu * mu;
            float rs = rsqrtf(var + EPS_);
            #pragma unroll
            for (int n = 0; n < 4; ++n) {
                int col = wc * 64 + n * 16 + l15;
                float lnv = (acc0[m][n][j] - mu) * rs * ln2w[col] + ln2b[col];
                *(short*)(AsB + row * 256 + ((col * 2) ^ X16(row))) = f2b(lnv);
            }
        }

    // ---- phase 1: fc1 + gelu -> GL ----
    #pragma unroll 1
    for (int c = 0; c < 4; ++c) {
        __syncthreads();
        MSTAGE((const char*)W1t + (size_t)c * 32768, 256, BsB, 8);
        asm volatile("s_waitcnt vmcnt(0)" ::: "memory");
        __syncthreads();
        f32x4 acc1[M_][4];
        #pragma unroll
        for (int m = 0; m < M_; ++m)
            #pragma unroll
            for (int n = 0; n < 4; ++n) acc1[m][n] = f32x4{0.f, 0.f, 0.f, 0.f};
        #pragma unroll
        for (int kk = 0; kk < 4; ++kk) {
            bf16x8 a[M_], b[4];
            int cb = kk * 64 + lhi * 16;
            #pragma unroll
            for (int m = 0; m < M_; ++m) {
                int row = wr * RW + m * 16 + l15;
                a[m] = *(const bf16x8*)(AsB + row * 256 + (cb ^ X16(row)));
            }
            #pragma unroll
            for (int n = 0; n < 4; ++n) {
                int rb = wc * 64 + n * 16 + l15;
                b[n] = *(const bf16x8*)(BsB + rb * 256 + (cb ^ X16(rb)));
            }
            #pragma unroll
            for (int m = 0; m < M_; ++m)
                #pragma unroll
                for (int n = 0; n < 4; ++n)
                    acc1[m][n] = __builtin_amdgcn_mfma_f32_16x16x32_bf16(a[m], b[n], acc1[m][n], 0, 0, 0);
        }
        #pragma unroll
        for (int m = 0; m < M_; ++m)
            #pragma unroll
            for (int n = 0; n < 4; ++n) {
                int col = c * 128 + wc * 64 + n * 16 + l15;
                float bv = b1[col];
                #pragma unroll
                for (int j = 0; j < 4; ++j) {
                    int row = wr * RW + m * 16 + lhi * 4 + j;
                    float v = gelu_f(acc1[m][n][j] + bv);
                    *(short*)(GLB + row * 1024 + ((col * 2) ^ X16(row))) = f2b(v);
                }
            }
    }

    // ---- phase 2: fc2 ----
    f32x4 acc2[M_][4];
    #pragma unroll
    for (int m = 0; m < M_; ++m)
        #pragma unroll
        for (int n = 0; n < 4; ++n) acc2[m][n] = f32x4{0.f, 0.f, 0.f, 0.f};
    #pragma unroll 1
    for (int kc = 0; kc < 4; ++kc) {
        __syncthreads();
        MSTAGE((const char*)W2t + kc * 256, 1024, BsB, 8);
        asm volatile("s_waitcnt vmcnt(0)" ::: "memory");
        __syncthreads();
        #pragma unroll
        for (int kk = 0; kk < 4; ++kk) {
            bf16x8 a[M_], b[4];
            int cb = kk * 64 + lhi * 16;
            #pragma unroll
            for (int m = 0; m < M_; ++m) {
                int row = wr * RW + m * 16 + l15;
                a[m] = *(const bf16x8*)(GLB + row * 1024 + ((kc * 256 + cb) ^ X16(row)));
            }
            #pragma unroll
            for (int n = 0; n < 4; ++n) {
                int rb = wc * 64 + n * 16 + l15;
                b[n] = *(const bf16x8*)(BsB + rb * 256 + (cb ^ X16(rb)));
            }
            #pragma unroll
            for (int m = 0; m < M_; ++m)
                #pragma unroll
                for (int n = 0; n < 4; ++n)
                    acc2[m][n] = __builtin_amdgcn_mfma_f32_16x16x32_bf16(a[m], b[n], acc2[m][n], 0, 0, 0);
        }
    }

    // ---- final epilogue ----
    #pragma unroll
    for (int m = 0; m < M_; ++m)
        #pragma unroll
        for (int n = 0; n < 4; ++n) {
            int col = wc * 64 + n * 16 + l15;
            float bv = b2[col];
            #pragma unroll
            for (int j = 0; j < 4; ++j) {
                acc2[m][n][j] += bv + acc0[m][n][j];
                if (FIN == 0) {
                    int rr = bm + wr * RW + m * 16 + lhi * 4 + j;
                    if (rr < M) resid[(size_t)rr * 128 + col] = acc2[m][n][j];
                }
            }
        }
    __syncthreads();
    float* sst2 = (float*)GL;
    #pragma unroll
    for (int m = 0; m < M_; ++m)
        #pragma unroll
        for (int j = 0; j < 4; ++j) {
            float ps = 0.f, pq = 0.f;
            #pragma unroll
            for (int n = 0; n < 4; ++n) { float t0 = acc2[m][n][j]; ps += t0; pq += t0 * t0; }
            #pragma unroll
            for (int o = 1; o < 16; o <<= 1) { ps += __shfl_xor(ps, o); pq += __shfl_xor(pq, o); }
            if (l15 == 0) {
                int row = wr * RW + m * 16 + lhi * 4 + j;
                sst2[row * 4 + wc * 2 + 0] = ps;
                sst2[row * 4 + wc * 2 + 1] = pq;
            }
        }
    __syncthreads();
    float pwl[4];
    if (FIN == 2) {
        #pragma unroll
        for (int n = 0; n < 4; ++n) pwl[n] = pwv[wc * 64 + n * 16 + l15];
    }
    float pp[M_][4];
    #pragma unroll
    for (int m = 0; m < M_; ++m)
        #pragma unroll
        for (int j = 0; j < 4; ++j) {
            int row = wr * RW + m * 16 + lhi * 4 + j;
            int rr = bm + row;
            float s0 = sst2[row * 4 + 0] + sst2[row * 4 + 2];
            float q0 = sst2[row * 4 + 1] + sst2[row * 4 + 3];
            float mu = s0 * (1.0f / 128.0f);
            float var = q0 * (1.0f / 128.0f) - mu * mu;
            float rs = rsqrtf(var + EPS_);
            float pacc = 0.f;
            #pragma unroll
            for (int n = 0; n < 4; ++n) {
                int col = wc * 64 + n * 16 + l15;
                float lnv = (acc2[m][n][j] - mu) * rs * lnfw[col] + lnfb[col];
                if (FIN != 2) {
                    if (rr < M) {
                        Lout[(size_t)rr * 128 + col] = f2b(lnv);
                        if (FIN == 1 && (rr % NENC_) == 0)
                            predp[(rr / NENC_) * 128 + col] = lnv;   // cls_out
                    }
                } else {
                    pacc += lnv * pwl[n];
                }
            }
            pp[m][j] = pacc;
        }
    if (FIN == 2) {
        float* sp = (float*)GL + 256;
        #pragma unroll
        for (int m = 0; m < M_; ++m)
            #pragma unroll
            for (int j = 0; j < 4; ++j) {
                float v2 = pp[m][j];
                #pragma unroll
                for (int o = 1; o < 16; o <<= 1) v2 += __shfl_xor(v2, o);
                if (l15 == 0) {
                    int row = wr * RW + m * 16 + lhi * 4 + j;
                    sp[row * 2 + wc] = v2;
                }
            }
        __syncthreads();
        if (tid < 64) {
            float s2 = 0.f;
            if (tid < MT) {
                int gr = bm + tid;
                float pred = sp[tid * 2] + sp[tid * 2 + 1] + pbv[0];
                predp[gr] = pred;
                float dd = pred - xin[gr];
                float msk = (rankp[gr] >= KEEP_) ? 1.0f : 0.0f;
                s2 = dd * dd * msk;
            }
            #pragma unroll
            for (int o = 1; o < 64; o <<= 1) s2 += __shfl_xor(s2, o);
            if (tid == 0) bsumsp[blockIdx.x] = s2;
        }
    }
#undef MSTAGE
}

// ---------------------------------------------------------------------------
// MFMA flash attention, split-KV, exp2-domain.
// Stage 128 KV rows per barrier-pair (R17 layout), process as TWO serialized
// 64-row subtiles with the R16 softmax body (keeps VGPR at the 64-tile level).
// TAIL=0: N divisible by 128.
// ---------------------------------------------------------------------------
template<int TAIL>
__global__ __launch_bounds__(256) void attn_mfma_kernel(
    const short* __restrict__ qkv, int N, int rowsTot,
    float* __restrict__ accp, float* __restrict__ mlp) {
    int h = blockIdx.y, b = blockIdx.z;
    int tid = threadIdx.x;
    int lane = tid & 63, wid = tid >> 6;
    int l15 = lane & 15, lhi = lane >> 4;
    __shared__ __align__(16) short smem[2][4096];   // per buf: K[128][16] | V[128][16]

    const short* base = qkv + (size_t)b * N * 384;
    int qt = blockIdx.x >> 1;
    int half = blockIdx.x & 1;

    int q0w = qt * 64 + wid * 16;
    int qi = q0w + l15;
    int qc = qi < N ? qi : N - 1;
    bf16x8 qf = *(const bf16x8*)(base + (size_t)qc * 384 + h * 16 + (lhi & 1) * 8);
    if (lhi >= 2) qf = bf16x8{0, 0, 0, 0, 0, 0, 0, 0};

    bool isK = (wid < 2);
    int r64 = ((wid & 1) << 5) | (lane >> 1);
    int hb = lane & 1;
    int t_ = r64 >> 4, rr = r64 & 15;
    int gp = ((t_ >> 1) << 5) | ((rr >> 2) << 3) | ((t_ & 1) << 2) | (rr & 3);
    int vp = r64 ^ ((r64 >> 3) & 3);           // V row perm (involution)
    int grow = isK ? gp : vp;
    int soff = (isK ? 128 : 256) + h * 16 + hb * 8;
    int ldsWaveOff = (isK ? 0 : 4096) + ((wid & 1) << 10);   // bytes within buf

    f32x4 acc = f32x4{0.f, 0.f, 0.f, 0.f};
    float mrun = -1e30f, lrun = 0.f;
    int nktT = (N + 127) >> 7;
    int lo = half * (nktT >> 1);
    int hi = half ? nktT : (nktT >> 1);

#define STAGE(KT, BUFI) do {                                                        \
        int ra_ = (KT) * 128 + grow;                                                \
        int rb_ = ra_ + 64;                                                         \
        ra_ = ra_ < N ? ra_ : N - 1;                                                \
        rb_ = rb_ < N ? rb_ : N - 1;                                                \
        __builtin_amdgcn_global_load_lds(                                           \
            (const __attribute__((address_space(1))) void*)(base + (size_t)ra_ * 384 + soff), \
            (__attribute__((address_space(3))) void*)((char*)&smem[BUFI][0] + ldsWaveOff), 16, 0, 0); \
        __builtin_amdgcn_global_load_lds(                                           \
            (const __attribute__((address_space(1))) void*)(base + (size_t)rb_ * 384 + soff), \
            (__attribute__((address_space(3))) void*)((char*)&smem[BUFI][0] + ldsWaveOff + 2048), 16, 0, 0); \
    } while (0)

    STAGE(lo, 0);
    for (int kt = lo; kt < hi; ++kt) {
        int bf = (kt - lo) & 1;
        if (kt + 1 < hi) {
            STAGE(kt + 1, bf ^ 1);
            asm volatile("s_waitcnt vmcnt(2)" ::: "memory");
        } else {
            asm volatile("s_waitcnt vmcnt(0)" ::: "memory");
        }
        __builtin_amdgcn_s_barrier();
        asm volatile("" ::: "memory");

        const short* kb = smem[bf];          // K rows 0..127 (subtile s at +s*1024)
        const short* vb = kb + 2048;         // V rows 0..127 (subtile s at +s*1024)

        #pragma unroll
        for (int s = 0; s < 2; ++s) {
            const short* kbs = kb + s * 1024;
            const short* vbs = vb + s * 1024;

            f32x4 s4[4];
            __builtin_amdgcn_s_setprio(1);
            #pragma unroll
            for (int t = 0; t < 4; ++t) {
                bf16x8 kf = *(const bf16x8*)(kbs + (t * 16 + l15) * 16 + (lhi & 1) * 8);
                s4[t] = __builtin_amdgcn_mfma_f32_16x16x32_bf16(kf, qf, f32x4{0.f, 0.f, 0.f, 0.f}, 0, 0, 0);
            }
            __builtin_amdgcn_s_setprio(0);

            int kv0 = kt * 128 + s * 64;
            float pvv[4][4];
            float mx = -1e30f;
            #pragma unroll
            for (int t = 0; t < 4; ++t)
                #pragma unroll
                for (int r = 0; r < 4; ++r) {
                    float v = s4[t][r];
                    if (TAIL) {
                        if (kv0 + 64 > N) {
                            int kvg = ((t >> 1) << 5) | (lhi << 3) | ((t & 1) << 2) | r;
                            if (kv0 + kvg >= N) v = -1e30f;
                        }
                    }
                    pvv[t][r] = v;
                    mx = fmaxf(mx, v);
                }
            mx = fmaxf(mx, __shfl_xor(mx, 16));
            mx = fmaxf(mx, __shfl_xor(mx, 32));
            if (!__all(mx - mrun <= 8.0f)) {            // defer-max (T13)
                float mnew = fmaxf(mrun, mx);
                float fr = fexp2(mrun - mnew);
                mrun = mnew;
                lrun *= fr;
                acc[0] *= fr; acc[1] *= fr; acc[2] *= fr; acc[3] *= fr;
            }
            float psum = 0.f;
            #pragma unroll
            for (int t = 0; t < 4; ++t)
                #pragma unroll
                for (int r = 0; r < 4; ++r) {
                    float pp = fexp2(pvv[t][r] - mrun);
                    pvv[t][r] = pp;
                    psum += pp;
                }
            lrun += psum;

            union { bf16x8 v8; unsigned u[4]; } pa0u, pa1u;
            pa0u.u[0] = cvtpk(pvv[0][0], pvv[0][1]);
            pa0u.u[1] = cvtpk(pvv[0][2], pvv[0][3]);
            pa0u.u[2] = cvtpk(pvv[1][0], pvv[1][1]);
            pa0u.u[3] = cvtpk(pvv[1][2], pvv[1][3]);
            pa1u.u[0] = cvtpk(pvv[2][0], pvv[2][1]);
            pa1u.u[1] = cvtpk(pvv[2][2], pvv[2][3]);
            pa1u.u[2] = cvtpk(pvv[3][0], pvv[3][1]);
            pa1u.u[3] = cvtpk(pvv[3][2], pvv[3][3]);

            bf16x8 vf0, vf1;
            #pragma unroll
            for (int i2 = 0; i2 < 8; ++i2) {
                int pr = lhi * 8 + (i2 ^ lhi);
                vf0[i2] = vbs[pr * 16 + l15];
                vf1[i2] = vbs[(32 + pr) * 16 + l15];
            }
            __builtin_amdgcn_s_setprio(1);
            acc = __builtin_amdgcn_mfma_f32_16x16x32_bf16(vf0, pa0u.v8, acc, 0, 0, 0);
            acc = __builtin_amdgcn_mfma_f32_16x16x32_bf16(vf1, pa1u.v8, acc, 0, 0, 0);
            __builtin_amdgcn_s_setprio(0);
        }

        asm volatile("s_waitcnt lgkmcnt(0)" ::: "memory");
        __builtin_amdgcn_s_barrier();
        asm volatile("" ::: "memory");
    }
#undef STAGE

    lrun += __shfl_xor(lrun, 16);
    lrun += __shfl_xor(lrun, 32);
    if (qi < N) {
        size_t row = (size_t)b * N + qi;
        *(f32x4*)(accp + ((size_t)half * rowsTot + row) * 128 + h * 16 + lhi * 4) = acc;
        if (lhi == 0) {
            float* mlq = mlp + ((size_t)half * rowsTot + row) * 16 + h * 2;
            mlq[0] = mrun;
            mlq[1] = lrun;
        }
    }
}

// ---------------------------------------------------------------------------
__global__ void loss_fin_kernel(const float* __restrict__ bs, float* __restrict__ out0) {
    int t = threadIdx.x;   // 64
    float s = bs[t] + bs[t + 64] + bs[t + 128] + bs[t + 192];
    #pragma unroll
    for (int o = 1; o < 64; o <<= 1) s += __shfl_xor(s, o);
    if (t == 0) out0[0] = s * (1.0f / 6144.0f);
}

// ---------------------------------------------------------------------------
extern "C" void kernel_launch(void* const* d_in, const int* in_sizes, int n_in,
                              void* d_out, int out_size, void* d_ws, size_t ws_size,
                              hipStream_t stream) {
    const float* x     = (const float*)d_in[0];
    const float* noise = (const float*)d_in[1];
    const float* pos   = (const float*)d_in[2];
    const float* cls   = (const float*)d_in[3];
    const float* eew   = (const float*)d_in[4];
    const float* eeb   = (const float*)d_in[5];
    const float* nw    = (const float*)d_in[6];
    const float* nb    = (const float*)d_in[7];
    const float* dew   = (const float*)d_in[8];
    const float* deb   = (const float*)d_in[9];
    const float* mtok  = (const float*)d_in[10];
    const float* dnw   = (const float*)d_in[11];
    const float* dnb   = (const float*)d_in[12];
    const float* pw    = (const float*)d_in[13];
    const float* pb    = (const float*)d_in[14];
    const float* eln1w = (const float*)d_in[15];
    const float* eln1b = (const float*)d_in[16];
    const float* eqkvw = (const float*)d_in[17];
    const float* eqkvb = (const float*)d_in[18];
    const float* eprjw = (const float*)d_in[19];
    const float* eprjb = (const float*)d_in[20];
    const float* eln2w = (const float*)d_in[21];
    const float* eln2b = (const float*)d_in[22];
    const float* ef1w  = (const float*)d_in[23];
    const float* ef1b  = (const float*)d_in[24];
    const float* ef2w  = (const float*)d_in[25];
    const float* ef2b  = (const float*)d_in[26];
    const float* dln1w = (const float*)d_in[27];
    const float* dln1b = (const float*)d_in[28];
    const float* dqkvw = (const float*)d_in[29];
    const float* dqkvb = (const float*)d_in[30];
    const float* dprjw = (const float*)d_in[31];
    const float* dprjb = (const float*)d_in[32];
    const float* dln2w = (const float*)d_in[33];
    const float* dln2b = (const float*)d_in[34];
    const float* df1w  = (const float*)d_in[35];
    const float* df1b  = (const float*)d_in[36];
    const float* df2w  = (const float*)d_in[37];
    const float* df2b  = (const float*)d_in[38];

    char* ws = (char*)d_ws;
    int*   rank    = (int*)(ws + 0);              // 32768
    int*   keep    = (int*)(ws + 32768);          // 8192
    float* bsums   = (float*)(ws + 40960);        // 8192
    float* enc_x   = (float*)(ws + 49152);        // 1050624
    float* decx    = (float*)(ws + 1099776);      // 4194304
    short* qkvb16  = (short*)(ws + 5294080);      // 6291456
    short* attnb16 = (short*)(ws + 11585536);     // 2097152 (unused now)
    short* lnb16   = (short*)(ws + 13682688);     // 2097152
    short* scr     = (short*)(ws + 15779840);     // 8388608  (accp partials)
    short* latb16  = (short*)(ws + 24168448);     // 557056
    float* demb    = (float*)(ws + 24725504);     // 1050624
    short* eqkvT   = (short*)(ws + 25776128);     // 589824
    short* eprjT   = (short*)(ws + 26365952);     // 196608
    short* ef1T    = (short*)(ws + 26562560);     // 786432
    short* ef2T    = (short*)(ws + 27348992);     // 786432
    short* dqkvT   = (short*)(ws + 28135424);     // 196608
    short* dprjT   = (short*)(ws + 28332032);     // 65536
    short* df1T    = (short*)(ws + 28397568);     // 262144
    short* df2T    = (short*)(ws + 28659712);     // 262144
    short* dembT   = (short*)(ws + 28921856);     // 32768
    float* mlp     = (float*)(ws + 28954624);     // 1048576 (2*8192*16*4) own region

    float* accp = (float*)scr;

    float* outp = (float*)d_out;
    float* pred_out = outp + 1;
    float* mask_out = outp + 1 + B_ * G_;
    float* cls_out  = outp + 1 + 2 * B_ * G_;

    prep_kernel<<<dim3(16, 16, 33), 256, 0, stream>>>(
        eqkvw, eprjw, ef1w, ef2w, dqkvw, dprjw, df1w, df2w, dew,
        eqkvT, eprjT, ef1T, ef2T, dqkvT, dprjT, df1T, df2T, dembT);

    rank_kernel<<<dim3(G_ / 256, B_), 1024, 0, stream>>>(noise, rank, keep, mask_out);
    embed_ln_kernel<<<dim3(NENC_, B_), 128, 0, stream>>>(x, pos, cls, eew, eeb, keep,
                                                         eln1w, eln1b, enc_x, lnb16);

    const int Menc = B_ * NENC_;                 // 2052
    const int gqE = (Menc + 31) / 32;            // 65  (BM=32)
    const int mbE = (Menc + 31) / 32;            // 65  (MT=32)
    const int nqtE = (NENC_ + 63) / 64;          // 9
    for (int L = 0; L < 6; ++L) {
        gemm_mfma_kernel<3, 32><<<dim3(gqE, 3), 256, 0, stream>>>(lnb16, eqkvT + (size_t)L * 384 * 128,
            eqkvb + L * 384, qkvb16, Menc, 128, 384);
        attn_mfma_kernel<1><<<dim3(2 * nqtE, NH_, B_), 256, 0, stream>>>(
            qkvb16, NENC_, Menc, accp, mlp);
        if (L < 5) {
            mega_mlp_kernel<0, 32><<<mbE, 256, 0, stream>>>(
                accp, mlp, Menc, eprjT + (size_t)L * 128 * 128, eprjb + L * D_, enc_x,
                ef1T + (size_t)L * 512 * 128, ef1b + L * HID_,
                ef2T + (size_t)L * 128 * 512, ef2b + L * D_,
                eln2w + L * D_, eln2b + L * D_,
                eln1w + (L + 1) * D_, eln1b + (L + 1) * D_, lnb16,
                nullptr, nullptr, nullptr, nullptr, nullptr, nullptr, Menc);
        } else {
            mega_mlp_kernel<1, 32><<<mbE, 256, 0, stream>>>(
                accp, mlp, Menc, eprjT + (size_t)L * 128 * 128, eprjb + L * D_, enc_x,
                ef1T + (size_t)L * 512 * 128, ef1b + L * HID_,
                ef2T + (size_t)L * 128 * 512, ef2b + L * D_,
                eln2w + L * D_, eln2b + L * D_,
                nw, nb, latb16,
                nullptr, nullptr, nullptr, nullptr, cls_out, nullptr, Menc);
        }
    }

    gemm_mfma_kernel<0, 32><<<dim3(gqE, 1), 256, 0, stream>>>(latb16, dembT, deb, demb, Menc, 128, 128);
    decbuild_ln_kernel<<<dim3(G_, B_), 128, 0, stream>>>(demb, mtok, pos, rank,
                                                         dln1w, dln1b, decx, lnb16);

    const int Mdec = B_ * G_;                    // 8192
    const int gqD = Mdec / 64;                   // 128 (BM=64)
    const int mbD = Mdec / 32;                   // 256 (MT=32)
    for (int L = 0; L < 2; ++L) {
        gemm_mfma_kernel<3, 64><<<dim3(gqD, 3), 256, 0, stream>>>(lnb16, dqkvT + (size_t)L * 384 * 128,
            dqkvb + L * 384, qkvb16, Mdec, 128, 384);
        attn_mfma_kernel<0><<<dim3(2 * (G_ / 64), NH_, B_), 256, 0, stream>>>(
            qkvb16, G_, Mdec, accp, mlp);
        if (L == 0) {
            mega_mlp_kernel<0, 32><<<mbD, 256, 0, stream>>>(
                accp, mlp, Mdec, dprjT + (size_t)L * 128 * 128, dprjb + L * D_, decx,
                df1T + (size_t)L * 512 * 128, df1b + L * HID_,
                df2T + (size_t)L * 128 * 512, df2b + L * D_,
                dln2w + L * D_, dln2b + L * D_,
                dln1w + D_, dln1b + D_, lnb16,
                nullptr, nullptr, nullptr, nullptr, nullptr, nullptr, Mdec);
        } else {
            mega_mlp_kernel<2, 32><<<mbD, 256, 0, stream>>>(
                accp, mlp, Mdec, dprjT + (size_t)L * 128 * 128, dprjb + L * D_, decx,
                df1T + (size_t)L * 512 * 128, df1b + L * HID_,
                df2T + (size_t)L * 128 * 512, df2b + L * D_,
                dln2w + L * D_, dln2b + L * D_,
                dnw, dnb, nullptr,
                pw, pb, x, rank, pred_out, bsums, Mdec);
        }
    }

    loss_fin_kernel<<<1, 64, 0, stream>>>(bsums, outp);
}

// Round 23
// 391.264 us; speedup vs baseline: 1.0136x; 1.0136x over previous
//
#include <hip/hip_runtime.h>
#include <math.h>

#define D_ 128
#define NH_ 8
#define G_ 2048
#define B_ 4
#define KEEP_ 512
#define NENC_ 513
#define HID_ 512
#define EPS_ 1e-5f

typedef short bf16x8 __attribute__((ext_vector_type(8)));
typedef short s16x4 __attribute__((ext_vector_type(4)));
typedef float f32x4 __attribute__((ext_vector_type(4)));
typedef unsigned u32x4 __attribute__((ext_vector_type(4)));

static __device__ __forceinline__ float b2f(short s) {
    union { float f; unsigned u; } v;
    v.u = ((unsigned)(unsigned short)s) << 16;
    return v.f;
}
static __device__ __forceinline__ short f2b(float f) {
    union { float f; unsigned u; } v;
    v.f = f;
    unsigned r = v.u + 0x7fffu + ((v.u >> 16) & 1u);   // RNE
    return (short)(r >> 16);
}
static __device__ __forceinline__ unsigned cvtpk(float lo, float hi) {
    unsigned r;
    asm("v_cvt_pk_bf16_f32 %0, %1, %2" : "=v"(r) : "v"(lo), "v"(hi));
    return r;
}
static __device__ __forceinline__ float fexp2(float x) {   // 2^x, 1 instr
    float r;
    asm("v_exp_f32 %0, %1" : "=v"(r) : "v"(x));
    return r;
}
static __device__ __forceinline__ float gelu_f(float v) {  // tanh-gelu via exp2
    float u = v * (0.7978845608f + 0.0356774081f * v * v);
    float t = fexp2(fminf(u * 2.8853900818f, 80.f));
    return v * t / (t + 1.0f);
}

#define QSCALE_LOG2 0.3606737602f   /* 0.25 * log2(e) */
#define X16(r) ((((r) >> 1) & 7) << 4)

// ---------------------------------------------------------------------------
// Stable rank. 1024 threads: 4 threads per i, 4 independent accumulator chains.
// ---------------------------------------------------------------------------
__global__ __launch_bounds__(1024) void rank_kernel(
    const float* __restrict__ noise, int* __restrict__ rank,
    int* __restrict__ keep_ids, float* __restrict__ mask_out) {
    int b = blockIdx.y;
    int tid = threadIdx.x;
    int li = tid & 255;
    int chunk = tid >> 8;
    int i = blockIdx.x * 256 + li;
    __shared__ float sn[G_];
    __shared__ int pr[1024];
    const float* row = noise + (size_t)b * G_;
    for (int j = tid; j < G_; j += 1024) sn[j] = row[j];
    __syncthreads();
    float vi = sn[i];
    int j0 = chunk * 512;
    int r0 = 0, r1 = 0, r2 = 0, r3 = 0;
    #pragma unroll 4
    for (int j = j0; j < j0 + 512; j += 4) {
        float a0 = sn[j], a1 = sn[j + 1], a2 = sn[j + 2], a3 = sn[j + 3];
        r0 += (a0 < vi) || (a0 == vi && (j + 0) < i);
        r1 += (a1 < vi) || (a1 == vi && (j + 1) < i);
        r2 += (a2 < vi) || (a2 == vi && (j + 2) < i);
        r3 += (a3 < vi) || (a3 == vi && (j + 3) < i);
    }
    pr[tid] = r0 + r1 + r2 + r3;
    __syncthreads();
    if (tid < 256) {
        int r = pr[tid] + pr[tid + 256] + pr[tid + 512] + pr[tid + 768];
        rank[b * G_ + i] = r;
        mask_out[b * G_ + i] = (r >= KEEP_) ? 1.0f : 0.0f;
        if (r < KEEP_) keep_ids[b * KEEP_ + r] = i;
    }
}

// ---------------------------------------------------------------------------
__global__ void prep_kernel(
    const float* __restrict__ eqkvw, const float* __restrict__ eprjw,
    const float* __restrict__ ef1w,  const float* __restrict__ ef2w,
    const float* __restrict__ dqkvw, const float* __restrict__ dprjw,
    const float* __restrict__ df1w,  const float* __restrict__ df2w,
    const float* __restrict__ dew,
    short* eqkvT, short* eprjT, short* ef1T, short* ef2T,
    short* dqkvT, short* dprjT, short* df1T, short* df2T, short* dembT) {
    int z = blockIdx.z;
    const float* s; short* d; int K, N;
    if (z < 6)       { int l = z;      s = eqkvw + (size_t)l * 128 * 384; d = eqkvT + (size_t)l * 384 * 128; K = 128; N = 384; }
    else if (z < 12) { int l = z - 6;  s = eprjw + (size_t)l * 128 * 128; d = eprjT + (size_t)l * 128 * 128; K = 128; N = 128; }
    else if (z < 18) { int l = z - 12; s = ef1w  + (size_t)l * 128 * 512; d = ef1T  + (size_t)l * 512 * 128; K = 128; N = 512; }
    else if (z < 24) { int l = z - 18; s = ef2w  + (size_t)l * 512 * 128; d = ef2T  + (size_t)l * 128 * 512; K = 512; N = 128; }
    else if (z < 26) { int l = z - 24; s = dqkvw + (size_t)l * 128 * 384; d = dqkvT + (size_t)l * 384 * 128; K = 128; N = 384; }
    else if (z < 28) { int l = z - 26; s = dprjw + (size_t)l * 128 * 128; d = dprjT + (size_t)l * 128 * 128; K = 128; N = 128; }
    else if (z < 30) { int l = z - 28; s = df1w  + (size_t)l * 128 * 512; d = df1T  + (size_t)l * 512 * 128; K = 128; N = 512; }
    else if (z < 32) { int l = z - 30; s = df2w  + (size_t)l * 512 * 128; d = df2T  + (size_t)l * 128 * 512; K = 512; N = 128; }
    else             { s = dew; d = dembT; K = 128; N = 128; }
    int n0 = blockIdx.x * 32, k0 = blockIdx.y * 32;
    if (n0 >= N || k0 >= K) return;
    __shared__ float t[32][33];
    int tx = threadIdx.x & 31, ty = threadIdx.x >> 5;
    #pragma unroll
    for (int i = 0; i < 32; i += 8)
        t[ty + i][tx] = s[(size_t)(k0 + ty + i) * N + n0 + tx];
    __syncthreads();
    #pragma unroll
    for (int i = 0; i < 32; i += 8)
        d[(size_t)(n0 + ty + i) * K + k0 + tx] = f2b(t[tx][ty + i]);
}

// ---------------------------------------------------------------------------
static __device__ __forceinline__ float row_ln_128(float v, int t, const float* g,
                                                   const float* bta, float* ss, float* qq) {
    float s = v;
    #pragma unroll
    for (int o = 1; o < 64; o <<= 1) s += __shfl_xor(s, o);
    if ((t & 63) == 0) ss[t >> 6] = s;
    __syncthreads();
    float mu = (ss[0] + ss[1]) * (1.0f / D_);
    float dv = v - mu;
    float q = dv * dv;
    #pragma unroll
    for (int o = 1; o < 64; o <<= 1) q += __shfl_xor(q, o);
    if ((t & 63) == 0) qq[t >> 6] = q;
    __syncthreads();
    float var = (qq[0] + qq[1]) * (1.0f / D_);
    return dv * rsqrtf(var + EPS_) * g[t] + bta[t];
}

// ---------------------------------------------------------------------------
__global__ void embed_ln_kernel(const float* __restrict__ x, const float* __restrict__ pos,
                                const float* __restrict__ cls, const float* __restrict__ ew,
                                const float* __restrict__ eb, const int* __restrict__ keep_ids,
                                const float* __restrict__ lnw, const float* __restrict__ lnb,
                                float* __restrict__ resid, short* __restrict__ lout) {
    int n = blockIdx.x, b = blockIdx.y;
    int t = threadIdx.x;
    float v;
    if (n == 0) v = cls[t];
    else {
        int i = keep_ids[b * KEEP_ + (n - 1)];
        v = x[b * G_ + i] * ew[t] + eb[t] + pos[(size_t)i * D_ + t];
    }
    size_t row = (size_t)b * NENC_ + n;
    resid[row * D_ + t] = v;
    __shared__ float ss[2], qq[2];
    lout[row * D_ + t] = f2b(row_ln_128(v, t, lnw, lnb, ss, qq));
}

// ---------------------------------------------------------------------------
__global__ void decbuild_ln_kernel(const float* __restrict__ dembed, const float* __restrict__ mask_token,
                                   const float* __restrict__ pos, const int* __restrict__ rank,
                                   const float* __restrict__ lnw, const float* __restrict__ lnb,
                                   float* __restrict__ resid, short* __restrict__ lout) {
    int i = blockIdx.x, b = blockIdx.y;
    int t = threadIdx.x;
    int r = rank[b * G_ + i];
    float v = (r < KEEP_) ? dembed[((size_t)b * NENC_ + 1 + r) * D_ + t] : mask_token[t];
    v += pos[(size_t)i * D_ + t];
    size_t row = (size_t)b * G_ + i;
    resid[row * D_ + t] = v;
    __shared__ float ss[2], qq[2];
    lout[row * D_ + t] = f2b(row_ln_128(v, t, lnw, lnb, ss, qq));
}

// ---------------------------------------------------------------------------
// bf16 MFMA GEMM, BM-row M-tile (32/64/128) x 128-col N-tile, BK=64.
// MODE 0: fp32 out   MODE 3: bf16 out (Q cols ×0.25*log2e when blockIdx.y==0)
// ---------------------------------------------------------------------------
template<int MODE, int BM>
__global__ __launch_bounds__(256) void gemm_mfma_kernel(
    const short* __restrict__ A, const short* __restrict__ Wt,
    const float* __restrict__ bias, void* __restrict__ Cout, int M, int K, int N) {
    constexpr int AM_ = (BM + 31) / 32;
    constexpr int RW = BM / 2;
    __shared__ short As[BM * 64];
    __shared__ short Bs[128 * 64];
    int tid = threadIdx.x;
    int lane = tid & 63, wid = tid >> 6;
    int wr = wid >> 1, wc = wid & 1;
    int bm = blockIdx.x * BM, bn = blockIdx.y * 128;
    int l15 = lane & 15, lhi = lane >> 4;
    f32x4 acc[AM_][4];
    #pragma unroll
    for (int m = 0; m < AM_; ++m)
        #pragma unroll
        for (int n = 0; n < 4; ++n) acc[m][n] = f32x4{0.f, 0.f, 0.f, 0.f};

    const char* Ab = (const char*)A;
    const char* Bb = (const char*)Wt;
    char* AsB = (char*)As;
    char* BsB = (char*)Bs;
    int p = tid * 16;
    int r0 = p >> 7, cb0 = p & 127;

    for (int k0 = 0; k0 < K; k0 += 64) {
        __syncthreads();
        #pragma unroll
        for (int it = 0; it < BM / 32; ++it) {
            int r = r0 + it * 32;
            int scb = cb0 ^ ((r & 7) << 4);
            __builtin_amdgcn_global_load_lds(
                (const __attribute__((address_space(1))) void*)(Ab + (((size_t)(bm + r) * K + k0) << 1) + scb),
                (__attribute__((address_space(3))) void*)(AsB + it * 4096 + (wid << 10)), 16, 0, 0);
        }
        #pragma unroll
        for (int it = 0; it < 4; ++it) {
            int r = r0 + it * 32;
            int scb = cb0 ^ ((r & 7) << 4);
            __builtin_amdgcn_global_load_lds(
                (const __attribute__((address_space(1))) void*)(Bb + (((size_t)(bn + r) * K + k0) << 1) + scb),
                (__attribute__((address_space(3))) void*)(BsB + it * 4096 + (wid << 10)), 16, 0, 0);
        }
        asm volatile("s_waitcnt vmcnt(0)" ::: "memory");
        __syncthreads();
        #pragma unroll
        for (int kk = 0; kk < 2; ++kk) {
            bf16x8 a[AM_], b[4];
            int cbb = kk * 64 + lhi * 16;
            #pragma unroll
            for (int m = 0; m < AM_; ++m) {
                int row = wr * RW + m * 16 + l15;
                a[m] = *(const bf16x8*)(AsB + row * 128 + (cbb ^ ((row & 7) << 4)));
            }
            #pragma unroll
            for (int m = 0; m < 4; ++m) {
                int rowb = wc * 64 + m * 16 + l15;
                b[m] = *(const bf16x8*)(BsB + rowb * 128 + (cbb ^ ((rowb & 7) << 4)));
            }
            #pragma unroll
            for (int m = 0; m < AM_; ++m)
                #pragma unroll
                for (int n = 0; n < 4; ++n)
                    acc[m][n] = __builtin_amdgcn_mfma_f32_16x16x32_bf16(a[m], b[n], acc[m][n], 0, 0, 0);
        }
    }

    float qsc = (MODE == 3 && blockIdx.y == 0) ? QSCALE_LOG2 : 1.0f;
    #pragma unroll
    for (int m = 0; m < AM_; ++m) {
        int rbase = bm + wr * RW + m * 16 + lhi * 4;
        #pragma unroll
        for (int n = 0; n < 4; ++n) {
            int col = bn + wc * 64 + n * 16 + l15;
            float bv = bias[col];
            #pragma unroll
            for (int j = 0; j < 4; ++j) {
                int rr = rbase + j;
                if (rr < M) {
                    float v = acc[m][n][j] + bv;
                    if (MODE == 3) ((short*)Cout)[(size_t)rr * N + col] = f2b(v * qsc);
                    else           ((float*)Cout)[(size_t)rr * N + col] = v;
                }
            }
        }
    }
}

// ---------------------------------------------------------------------------
// Mega layer-tail kernel with FUSED attn-combine A-staging:
// combine(accp,mlp) -> A-tile -> proj + resid + LN2 + fc1 + GELU + fc2 + resid + LN.
// MT = 32 (72KB LDS).  FIN 0: resid+LN  FIN 1: +cls  FIN 2: loss
// ---------------------------------------------------------------------------
template<int FIN, int MT>
__global__ __launch_bounds__(256) void mega_mlp_kernel(
    const float* __restrict__ accpp, const float* __restrict__ mlpp, int rowsTot,
    const short* __restrict__ prjT,
    const float* __restrict__ prjb, float* __restrict__ resid,
    const short* __restrict__ W1t, const float* __restrict__ b1,
    const short* __restrict__ W2t, const float* __restrict__ b2,
    const float* __restrict__ ln2w, const float* __restrict__ ln2b,
    const float* __restrict__ lnfw, const float* __restrict__ lnfb,
    short* __restrict__ Lout,
    const float* __restrict__ pwv, const float* __restrict__ pbv,
    const float* __restrict__ xin, const int* __restrict__ rankp,
    float* __restrict__ predp, float* __restrict__ bsumsp, int M) {
    constexpr int M_ = MT / 32;
    constexpr int RW = MT / 2;
    __shared__ short As[MT * 128];
    __shared__ short Bs[128 * 128];
    __shared__ short GL[MT * 512];
    char* AsB = (char*)As;
    char* BsB = (char*)Bs;
    char* GLB = (char*)GL;
    int tid = threadIdx.x;
    int lane = tid & 63, wid = tid >> 6;
    int wr = wid >> 1, wc = wid & 1;
    int l15 = lane & 15, lhi = lane >> 4;
    int bm = blockIdx.x * MT;
    int r0 = tid >> 4, cb0 = (tid & 15) << 4;

#define MSTAGE(SRCB, RSTRIDE, DST, ITERS) do {                                     \
        _Pragma("unroll")                                                          \
        for (int it = 0; it < (ITERS); ++it) {                                     \
            int r = r0 + it * 16;                                                  \
            int scb = cb0 ^ X16(r);                                                \
            __builtin_amdgcn_global_load_lds(                                      \
                (const __attribute__((address_space(1))) void*)((SRCB) + (size_t)r * (RSTRIDE) + scb), \
                (__attribute__((address_space(3))) void*)((DST) + it * 4096 + (tid << 4)), 16, 0, 0); \
        }                                                                          \
    } while (0)

    // ---- phase 0: fused attn-combine -> A-tile (ds_write), B via gload_lds ----
    #pragma unroll
    for (int it = 0; it < MT / 16; ++it) {
        int r = r0 + it * 16;
        int gr = bm + r; gr = gr < M ? gr : M - 1;
        int cg = (cb0 ^ X16(r)) >> 1;              // elem col (8-aligned, one head)
        int h = cg >> 4;
        const float* ml0 = mlpp + (size_t)gr * 16 + h * 2;
        const float* ml1 = ml0 + (size_t)rowsTot * 16;
        float m0 = ml0[0], l0 = ml0[1];
        float m1 = ml1[0], l1 = ml1[1];
        float M2 = fmaxf(m0, m1);
        float w0 = fexp2(m0 - M2), w1 = fexp2(m1 - M2);
        float rd = 1.0f / (w0 * l0 + w1 * l1);
        w0 *= rd; w1 *= rd;
        const float* a0p = accpp + (size_t)gr * 128 + cg;
        const float* a1p = a0p + (size_t)rowsTot * 128;
        f32x4 a0 = *(const f32x4*)a0p;
        f32x4 a0b = *(const f32x4*)(a0p + 4);
        f32x4 a1 = *(const f32x4*)a1p;
        f32x4 a1b = *(const f32x4*)(a1p + 4);
        u32x4 w;
        w[0] = cvtpk(w0 * a0[0] + w1 * a1[0], w0 * a0[1] + w1 * a1[1]);
        w[1] = cvtpk(w0 * a0[2] + w1 * a1[2], w0 * a0[3] + w1 * a1[3]);
        w[2] = cvtpk(w0 * a0b[0] + w1 * a1b[0], w0 * a0b[1] + w1 * a1b[1]);
        w[3] = cvtpk(w0 * a0b[2] + w1 * a1b[2], w0 * a0b[3] + w1 * a1b[3]);
        *(u32x4*)(AsB + it * 4096 + (tid << 4)) = w;
    }
    MSTAGE((const char*)prjT, 256, BsB, 8);
    asm volatile("s_waitcnt vmcnt(0)" ::: "memory");
    __syncthreads();
    f32x4 acc0[M_][4];
    #pragma unroll
    for (int m = 0; m < M_; ++m)
        #pragma unroll
        for (int n = 0; n < 4; ++n) acc0[m][n] = f32x4{0.f, 0.f, 0.f, 0.f};
    #pragma unroll
    for (int kk = 0; kk < 4; ++kk) {
        bf16x8 a[M_], b[4];
        int cb = kk * 64 + lhi * 16;
        #pragma unroll
        for (int m = 0; m < M_; ++m) {
            int row = wr * RW + m * 16 + l15;
            a[m] = *(const bf16x8*)(AsB + row * 256 + (cb ^ X16(row)));
        }
        #pragma unroll
        for (int n = 0; n < 4; ++n) {
            int rb = wc * 64 + n * 16 + l15;
            b[n] = *(const bf16x8*)(BsB + rb * 256 + (cb ^ X16(rb)));
        }
        #pragma unroll
        for (int m = 0; m < M_; ++m)
            #pragma unroll
            for (int n = 0; n < 4; ++n)
                acc0[m][n] = __builtin_amdgcn_mfma_f32_16x16x32_bf16(a[m], b[n], acc0[m][n], 0, 0, 0);
    }
    #pragma unroll
    for (int m = 0; m < M_; ++m)
        #pragma unroll
        for (int n = 0; n < 4; ++n) {
            int col = wc * 64 + n * 16 + l15;
            float bv = prjb[col];
            #pragma unroll
            for (int j = 0; j < 4; ++j) {
                int rr = bm + wr * RW + m * 16 + lhi * 4 + j;
                int rc = rr < M ? rr : M - 1;
                acc0[m][n][j] += bv + resid[(size_t)rc * 128 + col];
            }
        }
    float* sst = (float*)GL;
    #pragma unroll
    for (int m = 0; m < M_; ++m)
        #pragma unroll
        for (int j = 0; j < 4; ++j) {
            float ps = 0.f, pq = 0.f;
            #pragma unroll
            for (int n = 0; n < 4; ++n) { float t0 = acc0[m][n][j]; ps += t0; pq += t0 * t0; }
            #pragma unroll
            for (int o = 1; o < 16; o <<= 1) { ps += __shfl_xor(ps, o); pq += __shfl_xor(pq, o); }
            if (l15 == 0) {
                int row = wr * RW + m * 16 + lhi * 4 + j;
                sst[row * 4 + wc * 2 + 0] = ps;
                sst[row * 4 + wc * 2 + 1] = pq;
            }
        }
    __syncthreads();
    #pragma unroll
    for (int m = 0; m < M_; ++m)
        #pragma unroll
        for (int j = 0; j < 4; ++j) {
            int row = wr * RW + m * 16 + lhi * 4 + j;
            float s0 = sst[row * 4 + 0] + sst[row * 4 + 2];
            float q0 = sst[row * 4 + 1] + sst[row * 4 + 3];
            float mu = s0 * (1.0f / 128.0f);
            float var = q0 * (1.0f / 128.0f) - mu * mu;
            float rs = rsqrtf(var + EPS_);
            #pragma unroll
            for (int n = 0; n < 4; ++n) {
                int col = wc * 64 + n * 16 + l15;
                float lnv = (acc0[m][n][j] - mu) * rs * ln2w[col] + ln2b[col];
                *(short*)(AsB + row * 256 + ((col * 2) ^ X16(row))) = f2b(lnv);
            }
        }

    // ---- phase 1: fc1 + gelu -> GL ----
    #pragma unroll 1
    for (int c = 0; c < 4; ++c) {
        __syncthreads();
        MSTAGE((const char*)W1t + (size_t)c * 32768, 256, BsB, 8);
        asm volatile("s_waitcnt vmcnt(0)" ::: "memory");
        __syncthreads();
        f32x4 acc1[M_][4];
        #pragma unroll
        for (int m = 0; m < M_; ++m)
            #pragma unroll
            for (int n = 0; n < 4; ++n) acc1[m][n] = f32x4{0.f, 0.f, 0.f, 0.f};
        #pragma unroll
        for (int kk = 0; kk < 4; ++kk) {
            bf16x8 a[M_], b[4];
            int cb = kk * 64 + lhi * 16;
            #pragma unroll
            for (int m = 0; m < M_; ++m) {
                int row = wr * RW + m * 16 + l15;
                a[m] = *(const bf16x8*)(AsB + row * 256 + (cb ^ X16(row)));
            }
            #pragma unroll
            for (int n = 0; n < 4; ++n) {
                int rb = wc * 64 + n * 16 + l15;
                b[n] = *(const bf16x8*)(BsB + rb * 256 + (cb ^ X16(rb)));
            }
            #pragma unroll
            for (int m = 0; m < M_; ++m)
                #pragma unroll
                for (int n = 0; n < 4; ++n)
                    acc1[m][n] = __builtin_amdgcn_mfma_f32_16x16x32_bf16(a[m], b[n], acc1[m][n], 0, 0, 0);
        }
        #pragma unroll
        for (int m = 0; m < M_; ++m)
            #pragma unroll
            for (int n = 0; n < 4; ++n) {
                int col = c * 128 + wc * 64 + n * 16 + l15;
                float bv = b1[col];
                #pragma unroll
                for (int j = 0; j < 4; ++j) {
                    int row = wr * RW + m * 16 + lhi * 4 + j;
                    float v = gelu_f(acc1[m][n][j] + bv);
                    *(short*)(GLB + row * 1024 + ((col * 2) ^ X16(row))) = f2b(v);
                }
            }
    }

    // ---- phase 2: fc2 ----
    f32x4 acc2[M_][4];
    #pragma unroll
    for (int m = 0; m < M_; ++m)
        #pragma unroll
        for (int n = 0; n < 4; ++n) acc2[m][n] = f32x4{0.f, 0.f, 0.f, 0.f};
    #pragma unroll 1
    for (int kc = 0; kc < 4; ++kc) {
        __syncthreads();
        MSTAGE((const char*)W2t + kc * 256, 1024, BsB, 8);
        asm volatile("s_waitcnt vmcnt(0)" ::: "memory");
        __syncthreads();
        #pragma unroll
        for (int kk = 0; kk < 4; ++kk) {
            bf16x8 a[M_], b[4];
            int cb = kk * 64 + lhi * 16;
            #pragma unroll
            for (int m = 0; m < M_; ++m) {
                int row = wr * RW + m * 16 + l15;
                a[m] = *(const bf16x8*)(GLB + row * 1024 + ((kc * 256 + cb) ^ X16(row)));
            }
            #pragma unroll
            for (int n = 0; n < 4; ++n) {
                int rb = wc * 64 + n * 16 + l15;
                b[n] = *(const bf16x8*)(BsB + rb * 256 + (cb ^ X16(rb)));
            }
            #pragma unroll
            for (int m = 0; m < M_; ++m)
                #pragma unroll
                for (int n = 0; n < 4; ++n)
                    acc2[m][n] = __builtin_amdgcn_mfma_f32_16x16x32_bf16(a[m], b[n], acc2[m][n], 0, 0, 0);
        }
    }

    // ---- final epilogue ----
    #pragma unroll
    for (int m = 0; m < M_; ++m)
        #pragma unroll
        for (int n = 0; n < 4; ++n) {
            int col = wc * 64 + n * 16 + l15;
            float bv = b2[col];
            #pragma unroll
            for (int j = 0; j < 4; ++j) {
                acc2[m][n][j] += bv + acc0[m][n][j];
                if (FIN == 0) {
                    int rr = bm + wr * RW + m * 16 + lhi * 4 + j;
                    if (rr < M) resid[(size_t)rr * 128 + col] = acc2[m][n][j];
                }
            }
        }
    __syncthreads();
    float* sst2 = (float*)GL;
    #pragma unroll
    for (int m = 0; m < M_; ++m)
        #pragma unroll
        for (int j = 0; j < 4; ++j) {
            float ps = 0.f, pq = 0.f;
            #pragma unroll
            for (int n = 0; n < 4; ++n) { float t0 = acc2[m][n][j]; ps += t0; pq += t0 * t0; }
            #pragma unroll
            for (int o = 1; o < 16; o <<= 1) { ps += __shfl_xor(ps, o); pq += __shfl_xor(pq, o); }
            if (l15 == 0) {
                int row = wr * RW + m * 16 + lhi * 4 + j;
                sst2[row * 4 + wc * 2 + 0] = ps;
                sst2[row * 4 + wc * 2 + 1] = pq;
            }
        }
    __syncthreads();
    float pwl[4];
    if (FIN == 2) {
        #pragma unroll
        for (int n = 0; n < 4; ++n) pwl[n] = pwv[wc * 64 + n * 16 + l15];
    }
    float pp[M_][4];
    #pragma unroll
    for (int m = 0; m < M_; ++m)
        #pragma unroll
        for (int j = 0; j < 4; ++j) {
            int row = wr * RW + m * 16 + lhi * 4 + j;
            int rr = bm + row;
            float s0 = sst2[row * 4 + 0] + sst2[row * 4 + 2];
            float q0 = sst2[row * 4 + 1] + sst2[row * 4 + 3];
            float mu = s0 * (1.0f / 128.0f);
            float var = q0 * (1.0f / 128.0f) - mu * mu;
            float rs = rsqrtf(var + EPS_);
            float pacc = 0.f;
            #pragma unroll
            for (int n = 0; n < 4; ++n) {
                int col = wc * 64 + n * 16 + l15;
                float lnv = (acc2[m][n][j] - mu) * rs * lnfw[col] + lnfb[col];
                if (FIN != 2) {
                    if (rr < M) {
                        Lout[(size_t)rr * 128 + col] = f2b(lnv);
                        if (FIN == 1 && (rr % NENC_) == 0)
                            predp[(rr / NENC_) * 128 + col] = lnv;   // cls_out
                    }
                } else {
                    pacc += lnv * pwl[n];
                }
            }
            pp[m][j] = pacc;
        }
    if (FIN == 2) {
        float* sp = (float*)GL + 256;
        #pragma unroll
        for (int m = 0; m < M_; ++m)
            #pragma unroll
            for (int j = 0; j < 4; ++j) {
                float v2 = pp[m][j];
                #pragma unroll
                for (int o = 1; o < 16; o <<= 1) v2 += __shfl_xor(v2, o);
                if (l15 == 0) {
                    int row = wr * RW + m * 16 + lhi * 4 + j;
                    sp[row * 2 + wc] = v2;
                }
            }
        __syncthreads();
        if (tid < 64) {
            float s2 = 0.f;
            if (tid < MT) {
                int gr = bm + tid;
                float pred = sp[tid * 2] + sp[tid * 2 + 1] + pbv[0];
                predp[gr] = pred;
                float dd = pred - xin[gr];
                float msk = (rankp[gr] >= KEEP_) ? 1.0f : 0.0f;
                s2 = dd * dd * msk;
            }
            #pragma unroll
            for (int o = 1; o < 64; o <<= 1) s2 += __shfl_xor(s2, o);
            if (tid == 0) bsumsp[blockIdx.x] = s2;
        }
    }
#undef MSTAGE
}

// ---------------------------------------------------------------------------
// MFMA flash attention, 64-row KV tiles (R13/R16-verified) — used for ENC
// (N=513: even 4/5 tile split, minimal mask waste).
// ---------------------------------------------------------------------------
template<int TAIL>
__global__ __launch_bounds__(256) void attn_mfma_kernel(
    const short* __restrict__ qkv, int N, int rowsTot,
    float* __restrict__ accp, float* __restrict__ mlp) {
    int h = blockIdx.y, b = blockIdx.z;
    int tid = threadIdx.x;
    int lane = tid & 63, wid = tid >> 6;
    int l15 = lane & 15, lhi = lane >> 4;
    __shared__ __align__(16) short smem[2][2048];

    const short* base = qkv + (size_t)b * N * 384;
    int qt = blockIdx.x >> 1;
    int half = blockIdx.x & 1;

    int q0w = qt * 64 + wid * 16;
    int qi = q0w + l15;
    int qc = qi < N ? qi : N - 1;
    bf16x8 qf = *(const bf16x8*)(base + (size_t)qc * 384 + h * 16 + (lhi & 1) * 8);
    if (lhi >= 2) qf = bf16x8{0, 0, 0, 0, 0, 0, 0, 0};

    bool isK = (wid < 2);
    int r64 = ((wid & 1) << 5) | (lane >> 1);
    int hb = lane & 1;
    int t_ = r64 >> 4, rr = r64 & 15;
    int gp = ((t_ >> 1) << 5) | ((rr >> 2) << 3) | ((t_ & 1) << 2) | (rr & 3);
    int vp = r64 ^ ((r64 >> 3) & 3);           // V row perm (involution)
    int grow = isK ? gp : vp;
    int soff = (isK ? 128 : 256) + h * 16 + hb * 8;
    int ldsWaveOff = (isK ? 0 : 2048) + ((wid & 1) << 10);

    f32x4 acc = f32x4{0.f, 0.f, 0.f, 0.f};
    float mrun = -1e30f, lrun = 0.f;
    int nktT = (N + 63) >> 6;
    int lo = half * (nktT >> 1);
    int hi = half ? nktT : (nktT >> 1);

#define STAGE(KT, BUFI) do {                                                        \
        int row_ = (KT) * 64 + grow;                                                \
        row_ = row_ < N ? row_ : N - 1;                                             \
        __builtin_amdgcn_global_load_lds(                                           \
            (const __attribute__((address_space(1))) void*)(base + (size_t)row_ * 384 + soff), \
            (__attribute__((address_space(3))) void*)((char*)&smem[BUFI][0] + ldsWaveOff), 16, 0, 0); \
    } while (0)

    STAGE(lo, 0);
    for (int kt = lo; kt < hi; ++kt) {
        int bf = (kt - lo) & 1;
        if (kt + 1 < hi) {
            STAGE(kt + 1, bf ^ 1);
            asm volatile("s_waitcnt vmcnt(1)" ::: "memory");
        } else {
            asm volatile("s_waitcnt vmcnt(0)" ::: "memory");
        }
        __builtin_amdgcn_s_barrier();
        asm volatile("" ::: "memory");

        const short* kb = smem[bf];
        const short* vb = kb + 1024;

        f32x4 s4[4];
        __builtin_amdgcn_s_setprio(1);
        #pragma unroll
        for (int t = 0; t < 4; ++t) {
            bf16x8 kf = *(const bf16x8*)(kb + (t * 16 + l15) * 16 + (lhi & 1) * 8);
            s4[t] = __builtin_amdgcn_mfma_f32_16x16x32_bf16(kf, qf, f32x4{0.f, 0.f, 0.f, 0.f}, 0, 0, 0);
        }
        __builtin_amdgcn_s_setprio(0);

        int kv0 = kt * 64;
        float pvv[4][4];
        float mx = -1e30f;
        #pragma unroll
        for (int t = 0; t < 4; ++t)
            #pragma unroll
            for (int r = 0; r < 4; ++r) {
                float v = s4[t][r];
                if (TAIL) {
                    if (kv0 + 64 > N) {
                        int kvg = ((t >> 1) << 5) | (lhi << 3) | ((t & 1) << 2) | r;
                        if (kv0 + kvg >= N) v = -1e30f;
                    }
                }
                pvv[t][r] = v;
                mx = fmaxf(mx, v);
            }
        mx = fmaxf(mx, __shfl_xor(mx, 16));
        mx = fmaxf(mx, __shfl_xor(mx, 32));
        if (!__all(mx - mrun <= 8.0f)) {            // defer-max (T13)
            float mnew = fmaxf(mrun, mx);
            float fr = fexp2(mrun - mnew);
            mrun = mnew;
            lrun *= fr;
            acc[0] *= fr; acc[1] *= fr; acc[2] *= fr; acc[3] *= fr;
        }
        float psum = 0.f;
        #pragma unroll
        for (int t = 0; t < 4; ++t)
            #pragma unroll
            for (int r = 0; r < 4; ++r) {
                float pp = fexp2(pvv[t][r] - mrun);
                pvv[t][r] = pp;
                psum += pp;
            }
        lrun += psum;

        union { bf16x8 v8; unsigned u[4]; } pa0u, pa1u;
        pa0u.u[0] = cvtpk(pvv[0][0], pvv[0][1]);
        pa0u.u[1] = cvtpk(pvv[0][2], pvv[0][3]);
        pa0u.u[2] = cvtpk(pvv[1][0], pvv[1][1]);
        pa0u.u[3] = cvtpk(pvv[1][2], pvv[1][3]);
        pa1u.u[0] = cvtpk(pvv[2][0], pvv[2][1]);
        pa1u.u[1] = cvtpk(pvv[2][2], pvv[2][3]);
        pa1u.u[2] = cvtpk(pvv[3][0], pvv[3][1]);
        pa1u.u[3] = cvtpk(pvv[3][2], pvv[3][3]);

        bf16x8 vf0, vf1;
        #pragma unroll
        for (int i2 = 0; i2 < 8; ++i2) {
            int pr = lhi * 8 + (i2 ^ lhi);
            vf0[i2] = vb[pr * 16 + l15];
            vf1[i2] = vb[(32 + pr) * 16 + l15];
        }
        __builtin_amdgcn_s_setprio(1);
        acc = __builtin_amdgcn_mfma_f32_16x16x32_bf16(vf0, pa0u.v8, acc, 0, 0, 0);
        acc = __builtin_amdgcn_mfma_f32_16x16x32_bf16(vf1, pa1u.v8, acc, 0, 0, 0);
        __builtin_amdgcn_s_setprio(0);

        asm volatile("s_waitcnt lgkmcnt(0)" ::: "memory");
        __builtin_amdgcn_s_barrier();
        asm volatile("" ::: "memory");
    }
#undef STAGE

    lrun += __shfl_xor(lrun, 16);
    lrun += __shfl_xor(lrun, 32);
    if (qi < N) {
        size_t row = (size_t)b * N + qi;
        *(f32x4*)(accp + ((size_t)half * rowsTot + row) * 128 + h * 16 + lhi * 4) = acc;
        if (lhi == 0) {
            float* mlq = mlp + ((size_t)half * rowsTot + row) * 16 + h * 2;
            mlq[0] = mrun;
            mlq[1] = lrun;
        }
    }
}

// ---------------------------------------------------------------------------
// MFMA flash attention, 128-row staging processed as 2 serialized 64-row
// subtiles (R22-verified) — used for DEC (N=2048, divisible by 128).
// Halves barriers/vmcnt/loop overhead while keeping VGPR at the 64-tile level.
// ---------------------------------------------------------------------------
__global__ __launch_bounds__(256) void attn_mfma128_kernel(
    const short* __restrict__ qkv, int N, int rowsTot,
    float* __restrict__ accp, float* __restrict__ mlp) {
    int h = blockIdx.y, b = blockIdx.z;
    int tid = threadIdx.x;
    int lane = tid & 63, wid = tid >> 6;
    int l15 = lane & 15, lhi = lane >> 4;
    __shared__ __align__(16) short smem[2][4096];   // per buf: K[128][16] | V[128][16]

    const short* base = qkv + (size_t)b * N * 384;
    int qt = blockIdx.x >> 1;
    int half = blockIdx.x & 1;

    int q0w = qt * 64 + wid * 16;
    int qi = q0w + l15;
    bf16x8 qf = *(const bf16x8*)(base + (size_t)qi * 384 + h * 16 + (lhi & 1) * 8);
    if (lhi >= 2) qf = bf16x8{0, 0, 0, 0, 0, 0, 0, 0};

    bool isK = (wid < 2);
    int r64 = ((wid & 1) << 5) | (lane >> 1);
    int hb = lane & 1;
    int t_ = r64 >> 4, rr = r64 & 15;
    int gp = ((t_ >> 1) << 5) | ((rr >> 2) << 3) | ((t_ & 1) << 2) | (rr & 3);
    int vp = r64 ^ ((r64 >> 3) & 3);           // V row perm (involution)
    int grow = isK ? gp : vp;
    int soff = (isK ? 128 : 256) + h * 16 + hb * 8;
    int ldsWaveOff = (isK ? 0 : 4096) + ((wid & 1) << 10);   // bytes within buf

    f32x4 acc = f32x4{0.f, 0.f, 0.f, 0.f};
    float mrun = -1e30f, lrun = 0.f;
    int nktT = N >> 7;
    int lo = half * (nktT >> 1);
    int hi = half ? nktT : (nktT >> 1);

#define STAGE(KT, BUFI) do {                                                        \
        int ra_ = (KT) * 128 + grow;                                                \
        int rb_ = ra_ + 64;                                                         \
        __builtin_amdgcn_global_load_lds(                                           \
            (const __attribute__((address_space(1))) void*)(base + (size_t)ra_ * 384 + soff), \
            (__attribute__((address_space(3))) void*)((char*)&smem[BUFI][0] + ldsWaveOff), 16, 0, 0); \
        __builtin_amdgcn_global_load_lds(                                           \
            (const __attribute__((address_space(1))) void*)(base + (size_t)rb_ * 384 + soff), \
            (__attribute__((address_space(3))) void*)((char*)&smem[BUFI][0] + ldsWaveOff + 2048), 16, 0, 0); \
    } while (0)

    STAGE(lo, 0);
    for (int kt = lo; kt < hi; ++kt) {
        int bf = (kt - lo) & 1;
        if (kt + 1 < hi) {
            STAGE(kt + 1, bf ^ 1);
            asm volatile("s_waitcnt vmcnt(2)" ::: "memory");
        } else {
            asm volatile("s_waitcnt vmcnt(0)" ::: "memory");
        }
        __builtin_amdgcn_s_barrier();
        asm volatile("" ::: "memory");

        const short* kb = smem[bf];          // K rows 0..127 (subtile s at +s*1024)
        const short* vb = kb + 2048;         // V rows 0..127 (subtile s at +s*1024)

        #pragma unroll
        for (int s = 0; s < 2; ++s) {
            const short* kbs = kb + s * 1024;
            const short* vbs = vb + s * 1024;

            f32x4 s4[4];
            __builtin_amdgcn_s_setprio(1);
            #pragma unroll
            for (int t = 0; t < 4; ++t) {
                bf16x8 kf = *(const bf16x8*)(kbs + (t * 16 + l15) * 16 + (lhi & 1) * 8);
                s4[t] = __builtin_amdgcn_mfma_f32_16x16x32_bf16(kf, qf, f32x4{0.f, 0.f, 0.f, 0.f}, 0, 0, 0);
            }
            __builtin_amdgcn_s_setprio(0);

            float pvv[4][4];
            float mx = -1e30f;
            #pragma unroll
            for (int t = 0; t < 4; ++t)
                #pragma unroll
                for (int r = 0; r < 4; ++r) {
                    float v = s4[t][r];
                    pvv[t][r] = v;
                    mx = fmaxf(mx, v);
                }
            mx = fmaxf(mx, __shfl_xor(mx, 16));
            mx = fmaxf(mx, __shfl_xor(mx, 32));
            if (!__all(mx - mrun <= 8.0f)) {            // defer-max (T13)
                float mnew = fmaxf(mrun, mx);
                float fr = fexp2(mrun - mnew);
                mrun = mnew;
                lrun *= fr;
                acc[0] *= fr; acc[1] *= fr; acc[2] *= fr; acc[3] *= fr;
            }
            float psum = 0.f;
            #pragma unroll
            for (int t = 0; t < 4; ++t)
                #pragma unroll
                for (int r = 0; r < 4; ++r) {
                    float pp = fexp2(pvv[t][r] - mrun);
                    pvv[t][r] = pp;
                    psum += pp;
                }
            lrun += psum;

            union { bf16x8 v8; unsigned u[4]; } pa0u, pa1u;
            pa0u.u[0] = cvtpk(pvv[0][0], pvv[0][1]);
            pa0u.u[1] = cvtpk(pvv[0][2], pvv[0][3]);
            pa0u.u[2] = cvtpk(pvv[1][0], pvv[1][1]);
            pa0u.u[3] = cvtpk(pvv[1][2], pvv[1][3]);
            pa1u.u[0] = cvtpk(pvv[2][0], pvv[2][1]);
            pa1u.u[1] = cvtpk(pvv[2][2], pvv[2][3]);
            pa1u.u[2] = cvtpk(pvv[3][0], pvv[3][1]);
            pa1u.u[3] = cvtpk(pvv[3][2], pvv[3][3]);

            bf16x8 vf0, vf1;
            #pragma unroll
            for (int i2 = 0; i2 < 8; ++i2) {
                int pr = lhi * 8 + (i2 ^ lhi);
                vf0[i2] = vbs[pr * 16 + l15];
                vf1[i2] = vbs[(32 + pr) * 16 + l15];
            }
            __builtin_amdgcn_s_setprio(1);
            acc = __builtin_amdgcn_mfma_f32_16x16x32_bf16(vf0, pa0u.v8, acc, 0, 0, 0);
            acc = __builtin_amdgcn_mfma_f32_16x16x32_bf16(vf1, pa1u.v8, acc, 0, 0, 0);
            __builtin_amdgcn_s_setprio(0);
        }

        asm volatile("s_waitcnt lgkmcnt(0)" ::: "memory");
        __builtin_amdgcn_s_barrier();
        asm volatile("" ::: "memory");
    }
#undef STAGE

    lrun += __shfl_xor(lrun, 16);
    lrun += __shfl_xor(lrun, 32);
    {
        size_t row = (size_t)b * N + qi;
        *(f32x4*)(accp + ((size_t)half * rowsTot + row) * 128 + h * 16 + lhi * 4) = acc;
        if (lhi == 0) {
            float* mlq = mlp + ((size_t)half * rowsTot + row) * 16 + h * 2;
            mlq[0] = mrun;
            mlq[1] = lrun;
        }
    }
}

// ---------------------------------------------------------------------------
__global__ void loss_fin_kernel(const float* __restrict__ bs, float* __restrict__ out0) {
    int t = threadIdx.x;   // 64
    float s = bs[t] + bs[t + 64] + bs[t + 128] + bs[t + 192];
    #pragma unroll
    for (int o = 1; o < 64; o <<= 1) s += __shfl_xor(s, o);
    if (t == 0) out0[0] = s * (1.0f / 6144.0f);
}

// ---------------------------------------------------------------------------
extern "C" void kernel_launch(void* const* d_in, const int* in_sizes, int n_in,
                              void* d_out, int out_size, void* d_ws, size_t ws_size,
                              hipStream_t stream) {
    const float* x     = (const float*)d_in[0];
    const float* noise = (const float*)d_in[1];
    const float* pos   = (const float*)d_in[2];
    const float* cls   = (const float*)d_in[3];
    const float* eew   = (const float*)d_in[4];
    const float* eeb   = (const float*)d_in[5];
    const float* nw    = (const float*)d_in[6];
    const float* nb    = (const float*)d_in[7];
    const float* dew   = (const float*)d_in[8];
    const float* deb   = (const float*)d_in[9];
    const float* mtok  = (const float*)d_in[10];
    const float* dnw   = (const float*)d_in[11];
    const float* dnb   = (const float*)d_in[12];
    const float* pw    = (const float*)d_in[13];
    const float* pb    = (const float*)d_in[14];
    const float* eln1w = (const float*)d_in[15];
    const float* eln1b = (const float*)d_in[16];
    const float* eqkvw = (const float*)d_in[17];
    const float* eqkvb = (const float*)d_in[18];
    const float* eprjw = (const float*)d_in[19];
    const float* eprjb = (const float*)d_in[20];
    const float* eln2w = (const float*)d_in[21];
    const float* eln2b = (const float*)d_in[22];
    const float* ef1w  = (const float*)d_in[23];
    const float* ef1b  = (const float*)d_in[24];
    const float* ef2w  = (const float*)d_in[25];
    const float* ef2b  = (const float*)d_in[26];
    const float* dln1w = (const float*)d_in[27];
    const float* dln1b = (const float*)d_in[28];
    const float* dqkvw = (const float*)d_in[29];
    const float* dqkvb = (const float*)d_in[30];
    const float* dprjw = (const float*)d_in[31];
    const float* dprjb = (const float*)d_in[32];
    const float* dln2w = (const float*)d_in[33];
    const float* dln2b = (const float*)d_in[34];
    const float* df1w  = (const float*)d_in[35];
    const float* df1b  = (const float*)d_in[36];
    const float* df2w  = (const float*)d_in[37];
    const float* df2b  = (const float*)d_in[38];

    char* ws = (char*)d_ws;
    int*   rank    = (int*)(ws + 0);              // 32768
    int*   keep    = (int*)(ws + 32768);          // 8192
    float* bsums   = (float*)(ws + 40960);        // 8192
    float* enc_x   = (float*)(ws + 49152);        // 1050624
    float* decx    = (float*)(ws + 1099776);      // 4194304
    short* qkvb16  = (short*)(ws + 5294080);      // 6291456
    short* attnb16 = (short*)(ws + 11585536);     // 2097152 (unused now)
    short* lnb16   = (short*)(ws + 13682688);     // 2097152
    short* scr     = (short*)(ws + 15779840);     // 8388608  (accp partials)
    short* latb16  = (short*)(ws + 24168448);     // 557056
    float* demb    = (float*)(ws + 24725504);     // 1050624
    short* eqkvT   = (short*)(ws + 25776128);     // 589824
    short* eprjT   = (short*)(ws + 26365952);     // 196608
    short* ef1T    = (short*)(ws + 26562560);     // 786432
    short* ef2T    = (short*)(ws + 27348992);     // 786432
    short* dqkvT   = (short*)(ws + 28135424);     // 196608
    short* dprjT   = (short*)(ws + 28332032);     // 65536
    short* df1T    = (short*)(ws + 28397568);     // 262144
    short* df2T    = (short*)(ws + 28659712);     // 262144
    short* dembT   = (short*)(ws + 28921856);     // 32768
    float* mlp     = (float*)(ws + 28954624);     // 1048576 (2*8192*16*4) own region

    float* accp = (float*)scr;

    float* outp = (float*)d_out;
    float* pred_out = outp + 1;
    float* mask_out = outp + 1 + B_ * G_;
    float* cls_out  = outp + 1 + 2 * B_ * G_;

    prep_kernel<<<dim3(16, 16, 33), 256, 0, stream>>>(
        eqkvw, eprjw, ef1w, ef2w, dqkvw, dprjw, df1w, df2w, dew,
        eqkvT, eprjT, ef1T, ef2T, dqkvT, dprjT, df1T, df2T, dembT);

    rank_kernel<<<dim3(G_ / 256, B_), 1024, 0, stream>>>(noise, rank, keep, mask_out);
    embed_ln_kernel<<<dim3(NENC_, B_), 128, 0, stream>>>(x, pos, cls, eew, eeb, keep,
                                                         eln1w, eln1b, enc_x, lnb16);

    const int Menc = B_ * NENC_;                 // 2052
    const int gqE = (Menc + 31) / 32;            // 65  (BM=32)
    const int mbE = (Menc + 31) / 32;            // 65  (MT=32)
    const int nqtE = (NENC_ + 63) / 64;          // 9
    for (int L = 0; L < 6; ++L) {
        gemm_mfma_kernel<3, 32><<<dim3(gqE, 3), 256, 0, stream>>>(lnb16, eqkvT + (size_t)L * 384 * 128,
            eqkvb + L * 384, qkvb16, Menc, 128, 384);
        attn_mfma_kernel<1><<<dim3(2 * nqtE, NH_, B_), 256, 0, stream>>>(
            qkvb16, NENC_, Menc, accp, mlp);
        if (L < 5) {
            mega_mlp_kernel<0, 32><<<mbE, 256, 0, stream>>>(
                accp, mlp, Menc, eprjT + (size_t)L * 128 * 128, eprjb + L * D_, enc_x,
                ef1T + (size_t)L * 512 * 128, ef1b + L * HID_,
                ef2T + (size_t)L * 128 * 512, ef2b + L * D_,
                eln2w + L * D_, eln2b + L * D_,
                eln1w + (L + 1) * D_, eln1b + (L + 1) * D_, lnb16,
                nullptr, nullptr, nullptr, nullptr, nullptr, nullptr, Menc);
        } else {
            mega_mlp_kernel<1, 32><<<mbE, 256, 0, stream>>>(
                accp, mlp, Menc, eprjT + (size_t)L * 128 * 128, eprjb + L * D_, enc_x,
                ef1T + (size_t)L * 512 * 128, ef1b + L * HID_,
                ef2T + (size_t)L * 128 * 512, ef2b + L * D_,
                eln2w + L * D_, eln2b + L * D_,
                nw, nb, latb16,
                nullptr, nullptr, nullptr, nullptr, cls_out, nullptr, Menc);
        }
    }

    gemm_mfma_kernel<0, 32><<<dim3(gqE, 1), 256, 0, stream>>>(latb16, dembT, deb, demb, Menc, 128, 128);
    decbuild_ln_kernel<<<dim3(G_, B_), 128, 0, stream>>>(demb, mtok, pos, rank,
                                                         dln1w, dln1b, decx, lnb16);

    const int Mdec = B_ * G_;                    // 8192
    const int gqD = Mdec / 64;                   // 128 (BM=64)
    const int mbD = Mdec / 32;                   // 256 (MT=32)
    for (int L = 0; L < 2; ++L) {
        gemm_mfma_kernel<3, 64><<<dim3(gqD, 3), 256, 0, stream>>>(lnb16, dqkvT + (size_t)L * 384 * 128,
            dqkvb + L * 384, qkvb16, Mdec, 128, 384);
        attn_mfma128_kernel<<<dim3(2 * (G_ / 64), NH_, B_), 256, 0, stream>>>(
            qkvb16, G_, Mdec, accp, mlp);
        if (L == 0) {
            mega_mlp_kernel<0, 32><<<mbD, 256, 0, stream>>>(
                accp, mlp, Mdec, dprjT + (size_t)L * 128 * 128, dprjb + L * D_, decx,
                df1T + (size_t)L * 512 * 128, df1b + L * HID_,
                df2T + (size_t)L * 128 * 512, df2b + L * D_,
                dln2w + L * D_, dln2b + L * D_,
                dln1w + D_, dln1b + D_, lnb16,
                nullptr, nullptr, nullptr, nullptr, nullptr, nullptr, Mdec);
        } else {
            mega_mlp_kernel<2, 32><<<mbD, 256, 0, stream>>>(
                accp, mlp, Mdec, dprjT + (size_t)L * 128 * 128, dprjb + L * D_, decx,
                df1T + (size_t)L * 512 * 128, df1b + L * HID_,
                df2T + (size_t)L * 128 * 512, df2b + L * D_,
                dln2w + L * D_, dln2b + L * D_,
                dnw, dnb, nullptr,
                pw, pb, x, rank, pred_out, bsums, Mdec);
        }
    }

    loss_fin_kernel<<<1, 64, 0, stream>>>(bsums, outp);
}

// Round 24
// 387.988 us; speedup vs baseline: 1.0222x; 1.0084x over previous
//
#include <hip/hip_runtime.h>
#include <math.h>

#define D_ 128
#define NH_ 8
#define G_ 2048
#define B_ 4
#define KEEP_ 512
#define NENC_ 513
#define HID_ 512
#define EPS_ 1e-5f

typedef short bf16x8 __attribute__((ext_vector_type(8)));
typedef short s16x4 __attribute__((ext_vector_type(4)));
typedef float f32x4 __attribute__((ext_vector_type(4)));
typedef unsigned u32x4 __attribute__((ext_vector_type(4)));

static __device__ __forceinline__ float b2f(short s) {
    union { float f; unsigned u; } v;
    v.u = ((unsigned)(unsigned short)s) << 16;
    return v.f;
}
static __device__ __forceinline__ short f2b(float f) {
    union { float f; unsigned u; } v;
    v.f = f;
    unsigned r = v.u + 0x7fffu + ((v.u >> 16) & 1u);   // RNE
    return (short)(r >> 16);
}
static __device__ __forceinline__ unsigned cvtpk(float lo, float hi) {
    unsigned r;
    asm("v_cvt_pk_bf16_f32 %0, %1, %2" : "=v"(r) : "v"(lo), "v"(hi));
    return r;
}
static __device__ __forceinline__ float fexp2(float x) {   // 2^x, 1 instr
    float r;
    asm("v_exp_f32 %0, %1" : "=v"(r) : "v"(x));
    return r;
}
static __device__ __forceinline__ float gelu_f(float v) {  // tanh-gelu via exp2
    float u = v * (0.7978845608f + 0.0356774081f * v * v);
    float t = fexp2(fminf(u * 2.8853900818f, 80.f));
    return v * t / (t + 1.0f);
}

#define QSCALE_LOG2 0.3606737602f   /* 0.25 * log2(e) */
#define X16(r) ((((r) >> 1) & 7) << 4)

// ---------------------------------------------------------------------------
// Stable rank. 1024 threads: 4 threads per i, 4 independent accumulator chains.
// ---------------------------------------------------------------------------
__global__ __launch_bounds__(1024) void rank_kernel(
    const float* __restrict__ noise, int* __restrict__ rank,
    int* __restrict__ keep_ids, float* __restrict__ mask_out) {
    int b = blockIdx.y;
    int tid = threadIdx.x;
    int li = tid & 255;
    int chunk = tid >> 8;
    int i = blockIdx.x * 256 + li;
    __shared__ float sn[G_];
    __shared__ int pr[1024];
    const float* row = noise + (size_t)b * G_;
    for (int j = tid; j < G_; j += 1024) sn[j] = row[j];
    __syncthreads();
    float vi = sn[i];
    int j0 = chunk * 512;
    int r0 = 0, r1 = 0, r2 = 0, r3 = 0;
    #pragma unroll 4
    for (int j = j0; j < j0 + 512; j += 4) {
        float a0 = sn[j], a1 = sn[j + 1], a2 = sn[j + 2], a3 = sn[j + 3];
        r0 += (a0 < vi) || (a0 == vi && (j + 0) < i);
        r1 += (a1 < vi) || (a1 == vi && (j + 1) < i);
        r2 += (a2 < vi) || (a2 == vi && (j + 2) < i);
        r3 += (a3 < vi) || (a3 == vi && (j + 3) < i);
    }
    pr[tid] = r0 + r1 + r2 + r3;
    __syncthreads();
    if (tid < 256) {
        int r = pr[tid] + pr[tid + 256] + pr[tid + 512] + pr[tid + 768];
        rank[b * G_ + i] = r;
        mask_out[b * G_ + i] = (r >= KEEP_) ? 1.0f : 0.0f;
        if (r < KEEP_) keep_ids[b * KEEP_ + r] = i;
    }
}

// ---------------------------------------------------------------------------
__global__ void prep_kernel(
    const float* __restrict__ eqkvw, const float* __restrict__ eprjw,
    const float* __restrict__ ef1w,  const float* __restrict__ ef2w,
    const float* __restrict__ dqkvw, const float* __restrict__ dprjw,
    const float* __restrict__ df1w,  const float* __restrict__ df2w,
    const float* __restrict__ dew,
    short* eqkvT, short* eprjT, short* ef1T, short* ef2T,
    short* dqkvT, short* dprjT, short* df1T, short* df2T, short* dembT) {
    int z = blockIdx.z;
    const float* s; short* d; int K, N;
    if (z < 6)       { int l = z;      s = eqkvw + (size_t)l * 128 * 384; d = eqkvT + (size_t)l * 384 * 128; K = 128; N = 384; }
    else if (z < 12) { int l = z - 6;  s = eprjw + (size_t)l * 128 * 128; d = eprjT + (size_t)l * 128 * 128; K = 128; N = 128; }
    else if (z < 18) { int l = z - 12; s = ef1w  + (size_t)l * 128 * 512; d = ef1T  + (size_t)l * 512 * 128; K = 128; N = 512; }
    else if (z < 24) { int l = z - 18; s = ef2w  + (size_t)l * 512 * 128; d = ef2T  + (size_t)l * 128 * 512; K = 512; N = 128; }
    else if (z < 26) { int l = z - 24; s = dqkvw + (size_t)l * 128 * 384; d = dqkvT + (size_t)l * 384 * 128; K = 128; N = 384; }
    else if (z < 28) { int l = z - 26; s = dprjw + (size_t)l * 128 * 128; d = dprjT + (size_t)l * 128 * 128; K = 128; N = 128; }
    else if (z < 30) { int l = z - 28; s = df1w  + (size_t)l * 128 * 512; d = df1T  + (size_t)l * 512 * 128; K = 128; N = 512; }
    else if (z < 32) { int l = z - 30; s = df2w  + (size_t)l * 512 * 128; d = df2T  + (size_t)l * 128 * 512; K = 512; N = 128; }
    else             { s = dew; d = dembT; K = 128; N = 128; }
    int n0 = blockIdx.x * 32, k0 = blockIdx.y * 32;
    if (n0 >= N || k0 >= K) return;
    __shared__ float t[32][33];
    int tx = threadIdx.x & 31, ty = threadIdx.x >> 5;
    #pragma unroll
    for (int i = 0; i < 32; i += 8)
        t[ty + i][tx] = s[(size_t)(k0 + ty + i) * N + n0 + tx];
    __syncthreads();
    #pragma unroll
    for (int i = 0; i < 32; i += 8)
        d[(size_t)(n0 + ty + i) * K + k0 + tx] = f2b(t[tx][ty + i]);
}

// ---------------------------------------------------------------------------
static __device__ __forceinline__ float row_ln_128(float v, int t, const float* g,
                                                   const float* bta, float* ss, float* qq) {
    float s = v;
    #pragma unroll
    for (int o = 1; o < 64; o <<= 1) s += __shfl_xor(s, o);
    if ((t & 63) == 0) ss[t >> 6] = s;
    __syncthreads();
    float mu = (ss[0] + ss[1]) * (1.0f / D_);
    float dv = v - mu;
    float q = dv * dv;
    #pragma unroll
    for (int o = 1; o < 64; o <<= 1) q += __shfl_xor(q, o);
    if ((t & 63) == 0) qq[t >> 6] = q;
    __syncthreads();
    float var = (qq[0] + qq[1]) * (1.0f / D_);
    return dv * rsqrtf(var + EPS_) * g[t] + bta[t];
}

// ---------------------------------------------------------------------------
__global__ void embed_ln_kernel(const float* __restrict__ x, const float* __restrict__ pos,
                                const float* __restrict__ cls, const float* __restrict__ ew,
                                const float* __restrict__ eb, const int* __restrict__ keep_ids,
                                const float* __restrict__ lnw, const float* __restrict__ lnb,
                                float* __restrict__ resid, short* __restrict__ lout) {
    int n = blockIdx.x, b = blockIdx.y;
    int t = threadIdx.x;
    float v;
    if (n == 0) v = cls[t];
    else {
        int i = keep_ids[b * KEEP_ + (n - 1)];
        v = x[b * G_ + i] * ew[t] + eb[t] + pos[(size_t)i * D_ + t];
    }
    size_t row = (size_t)b * NENC_ + n;
    resid[row * D_ + t] = v;
    __shared__ float ss[2], qq[2];
    lout[row * D_ + t] = f2b(row_ln_128(v, t, lnw, lnb, ss, qq));
}

// ---------------------------------------------------------------------------
__global__ void decbuild_ln_kernel(const float* __restrict__ dembed, const float* __restrict__ mask_token,
                                   const float* __restrict__ pos, const int* __restrict__ rank,
                                   const float* __restrict__ lnw, const float* __restrict__ lnb,
                                   float* __restrict__ resid, short* __restrict__ lout) {
    int i = blockIdx.x, b = blockIdx.y;
    int t = threadIdx.x;
    int r = rank[b * G_ + i];
    float v = (r < KEEP_) ? dembed[((size_t)b * NENC_ + 1 + r) * D_ + t] : mask_token[t];
    v += pos[(size_t)i * D_ + t];
    size_t row = (size_t)b * G_ + i;
    resid[row * D_ + t] = v;
    __shared__ float ss[2], qq[2];
    lout[row * D_ + t] = f2b(row_ln_128(v, t, lnw, lnb, ss, qq));
}

// ---------------------------------------------------------------------------
// bf16 MFMA GEMM, BM-row M-tile (32/64/128) x 128-col N-tile, BK=64.
// MODE 0: fp32 out   MODE 3: bf16 out (Q cols ×0.25*log2e when blockIdx.y==0)
// ---------------------------------------------------------------------------
template<int MODE, int BM>
__global__ __launch_bounds__(256) void gemm_mfma_kernel(
    const short* __restrict__ A, const short* __restrict__ Wt,
    const float* __restrict__ bias, void* __restrict__ Cout, int M, int K, int N) {
    constexpr int AM_ = (BM + 31) / 32;
    constexpr int RW = BM / 2;
    __shared__ short As[BM * 64];
    __shared__ short Bs[128 * 64];
    int tid = threadIdx.x;
    int lane = tid & 63, wid = tid >> 6;
    int wr = wid >> 1, wc = wid & 1;
    int bm = blockIdx.x * BM, bn = blockIdx.y * 128;
    int l15 = lane & 15, lhi = lane >> 4;
    f32x4 acc[AM_][4];
    #pragma unroll
    for (int m = 0; m < AM_; ++m)
        #pragma unroll
        for (int n = 0; n < 4; ++n) acc[m][n] = f32x4{0.f, 0.f, 0.f, 0.f};

    const char* Ab = (const char*)A;
    const char* Bb = (const char*)Wt;
    char* AsB = (char*)As;
    char* BsB = (char*)Bs;
    int p = tid * 16;
    int r0 = p >> 7, cb0 = p & 127;

    for (int k0 = 0; k0 < K; k0 += 64) {
        __syncthreads();
        #pragma unroll
        for (int it = 0; it < BM / 32; ++it) {
            int r = r0 + it * 32;
            int scb = cb0 ^ ((r & 7) << 4);
            __builtin_amdgcn_global_load_lds(
                (const __attribute__((address_space(1))) void*)(Ab + (((size_t)(bm + r) * K + k0) << 1) + scb),
                (__attribute__((address_space(3))) void*)(AsB + it * 4096 + (wid << 10)), 16, 0, 0);
        }
        #pragma unroll
        for (int it = 0; it < 4; ++it) {
            int r = r0 + it * 32;
            int scb = cb0 ^ ((r & 7) << 4);
            __builtin_amdgcn_global_load_lds(
                (const __attribute__((address_space(1))) void*)(Bb + (((size_t)(bn + r) * K + k0) << 1) + scb),
                (__attribute__((address_space(3))) void*)(BsB + it * 4096 + (wid << 10)), 16, 0, 0);
        }
        asm volatile("s_waitcnt vmcnt(0)" ::: "memory");
        __syncthreads();
        #pragma unroll
        for (int kk = 0; kk < 2; ++kk) {
            bf16x8 a[AM_], b[4];
            int cbb = kk * 64 + lhi * 16;
            #pragma unroll
            for (int m = 0; m < AM_; ++m) {
                int row = wr * RW + m * 16 + l15;
                a[m] = *(const bf16x8*)(AsB + row * 128 + (cbb ^ ((row & 7) << 4)));
            }
            #pragma unroll
            for (int m = 0; m < 4; ++m) {
                int rowb = wc * 64 + m * 16 + l15;
                b[m] = *(const bf16x8*)(BsB + rowb * 128 + (cbb ^ ((rowb & 7) << 4)));
            }
            #pragma unroll
            for (int m = 0; m < AM_; ++m)
                #pragma unroll
                for (int n = 0; n < 4; ++n)
                    acc[m][n] = __builtin_amdgcn_mfma_f32_16x16x32_bf16(a[m], b[n], acc[m][n], 0, 0, 0);
        }
    }

    float qsc = (MODE == 3 && blockIdx.y == 0) ? QSCALE_LOG2 : 1.0f;
    #pragma unroll
    for (int m = 0; m < AM_; ++m) {
        int rbase = bm + wr * RW + m * 16 + lhi * 4;
        #pragma unroll
        for (int n = 0; n < 4; ++n) {
            int col = bn + wc * 64 + n * 16 + l15;
            float bv = bias[col];
            #pragma unroll
            for (int j = 0; j < 4; ++j) {
                int rr = rbase + j;
                if (rr < M) {
                    float v = acc[m][n][j] + bv;
                    if (MODE == 3) ((short*)Cout)[(size_t)rr * N + col] = f2b(v * qsc);
                    else           ((float*)Cout)[(size_t)rr * N + col] = v;
                }
            }
        }
    }
}

// ---------------------------------------------------------------------------
// Mega layer-tail kernel with FUSED attn-combine A-staging:
// B-stage (prjT) issued FIRST so its L2 latency hides under the combine phase.
// MT = 32 (72KB LDS).  FIN 0: resid+LN  FIN 1: +cls  FIN 2: loss
// ---------------------------------------------------------------------------
template<int FIN, int MT>
__global__ __launch_bounds__(256) void mega_mlp_kernel(
    const float* __restrict__ accpp, const float* __restrict__ mlpp, int rowsTot,
    const short* __restrict__ prjT,
    const float* __restrict__ prjb, float* __restrict__ resid,
    const short* __restrict__ W1t, const float* __restrict__ b1,
    const short* __restrict__ W2t, const float* __restrict__ b2,
    const float* __restrict__ ln2w, const float* __restrict__ ln2b,
    const float* __restrict__ lnfw, const float* __restrict__ lnfb,
    short* __restrict__ Lout,
    const float* __restrict__ pwv, const float* __restrict__ pbv,
    const float* __restrict__ xin, const int* __restrict__ rankp,
    float* __restrict__ predp, float* __restrict__ bsumsp, int M) {
    constexpr int M_ = MT / 32;
    constexpr int RW = MT / 2;
    __shared__ short As[MT * 128];
    __shared__ short Bs[128 * 128];
    __shared__ short GL[MT * 512];
    char* AsB = (char*)As;
    char* BsB = (char*)Bs;
    char* GLB = (char*)GL;
    int tid = threadIdx.x;
    int lane = tid & 63, wid = tid >> 6;
    int wr = wid >> 1, wc = wid & 1;
    int l15 = lane & 15, lhi = lane >> 4;
    int bm = blockIdx.x * MT;
    int r0 = tid >> 4, cb0 = (tid & 15) << 4;

#define MSTAGE(SRCB, RSTRIDE, DST, ITERS) do {                                     \
        _Pragma("unroll")                                                          \
        for (int it = 0; it < (ITERS); ++it) {                                     \
            int r = r0 + it * 16;                                                  \
            int scb = cb0 ^ X16(r);                                                \
            __builtin_amdgcn_global_load_lds(                                      \
                (const __attribute__((address_space(1))) void*)((SRCB) + (size_t)r * (RSTRIDE) + scb), \
                (__attribute__((address_space(3))) void*)((DST) + it * 4096 + (tid << 4)), 16, 0, 0); \
        }                                                                          \
    } while (0)

    // ---- phase 0: B-stage first (latency hides under combine), then combine ----
    MSTAGE((const char*)prjT, 256, BsB, 8);
    #pragma unroll
    for (int it = 0; it < MT / 16; ++it) {
        int r = r0 + it * 16;
        int gr = bm + r; gr = gr < M ? gr : M - 1;
        int cg = (cb0 ^ X16(r)) >> 1;              // elem col (8-aligned, one head)
        int h = cg >> 4;
        const float* ml0 = mlpp + (size_t)gr * 16 + h * 2;
        const float* ml1 = ml0 + (size_t)rowsTot * 16;
        float m0 = ml0[0], l0 = ml0[1];
        float m1 = ml1[0], l1 = ml1[1];
        float M2 = fmaxf(m0, m1);
        float w0 = fexp2(m0 - M2), w1 = fexp2(m1 - M2);
        float rd = 1.0f / (w0 * l0 + w1 * l1);
        w0 *= rd; w1 *= rd;
        const float* a0p = accpp + (size_t)gr * 128 + cg;
        const float* a1p = a0p + (size_t)rowsTot * 128;
        f32x4 a0 = *(const f32x4*)a0p;
        f32x4 a0b = *(const f32x4*)(a0p + 4);
        f32x4 a1 = *(const f32x4*)a1p;
        f32x4 a1b = *(const f32x4*)(a1p + 4);
        u32x4 w;
        w[0] = cvtpk(w0 * a0[0] + w1 * a1[0], w0 * a0[1] + w1 * a1[1]);
        w[1] = cvtpk(w0 * a0[2] + w1 * a1[2], w0 * a0[3] + w1 * a1[3]);
        w[2] = cvtpk(w0 * a0b[0] + w1 * a1b[0], w0 * a0b[1] + w1 * a1b[1]);
        w[3] = cvtpk(w0 * a0b[2] + w1 * a1b[2], w0 * a0b[3] + w1 * a1b[3]);
        *(u32x4*)(AsB + it * 4096 + (tid << 4)) = w;
    }
    asm volatile("s_waitcnt vmcnt(0)" ::: "memory");
    __syncthreads();
    f32x4 acc0[M_][4];
    #pragma unroll
    for (int m = 0; m < M_; ++m)
        #pragma unroll
        for (int n = 0; n < 4; ++n) acc0[m][n] = f32x4{0.f, 0.f, 0.f, 0.f};
    #pragma unroll
    for (int kk = 0; kk < 4; ++kk) {
        bf16x8 a[M_], b[4];
        int cb = kk * 64 + lhi * 16;
        #pragma unroll
        for (int m = 0; m < M_; ++m) {
            int row = wr * RW + m * 16 + l15;
            a[m] = *(const bf16x8*)(AsB + row * 256 + (cb ^ X16(row)));
        }
        #pragma unroll
        for (int n = 0; n < 4; ++n) {
            int rb = wc * 64 + n * 16 + l15;
            b[n] = *(const bf16x8*)(BsB + rb * 256 + (cb ^ X16(rb)));
        }
        #pragma unroll
        for (int m = 0; m < M_; ++m)
            #pragma unroll
            for (int n = 0; n < 4; ++n)
                acc0[m][n] = __builtin_amdgcn_mfma_f32_16x16x32_bf16(a[m], b[n], acc0[m][n], 0, 0, 0);
    }
    #pragma unroll
    for (int m = 0; m < M_; ++m)
        #pragma unroll
        for (int n = 0; n < 4; ++n) {
            int col = wc * 64 + n * 16 + l15;
            float bv = prjb[col];
            #pragma unroll
            for (int j = 0; j < 4; ++j) {
                int rr = bm + wr * RW + m * 16 + lhi * 4 + j;
                int rc = rr < M ? rr : M - 1;
                acc0[m][n][j] += bv + resid[(size_t)rc * 128 + col];
            }
        }
    float* sst = (float*)GL;
    #pragma unroll
    for (int m = 0; m < M_; ++m)
        #pragma unroll
        for (int j = 0; j < 4; ++j) {
            float ps = 0.f, pq = 0.f;
            #pragma unroll
            for (int n = 0; n < 4; ++n) { float t0 = acc0[m][n][j]; ps += t0; pq += t0 * t0; }
            #pragma unroll
            for (int o = 1; o < 16; o <<= 1) { ps += __shfl_xor(ps, o); pq += __shfl_xor(pq, o); }
            if (l15 == 0) {
                int row = wr * RW + m * 16 + lhi * 4 + j;
                sst[row * 4 + wc * 2 + 0] = ps;
                sst[row * 4 + wc * 2 + 1] = pq;
            }
        }
    __syncthreads();
    #pragma unroll
    for (int m = 0; m < M_; ++m)
        #pragma unroll
        for (int j = 0; j < 4; ++j) {
            int row = wr * RW + m * 16 + lhi * 4 + j;
            float s0 = sst[row * 4 + 0] + sst[row * 4 + 2];
            float q0 = sst[row * 4 + 1] + sst[row * 4 + 3];
            float mu = s0 * (1.0f / 128.0f);
            float var = q0 * (1.0f / 128.0f) - mu * mu;
            float rs = rsqrtf(var + EPS_);
            #pragma unroll
            for (int n = 0; n < 4; ++n) {
                int col = wc * 64 + n * 16 + l15;
                float lnv = (acc0[m][n][j] - mu) * rs * ln2w[col] + ln2b[col];
                *(short*)(AsB + row * 256 + ((col * 2) ^ X16(row))) = f2b(lnv);
            }
        }

    // ---- phase 1: fc1 + gelu -> GL ----
    #pragma unroll 1
    for (int c = 0; c < 4; ++c) {
        __syncthreads();
        MSTAGE((const char*)W1t + (size_t)c * 32768, 256, BsB, 8);
        asm volatile("s_waitcnt vmcnt(0)" ::: "memory");
        __syncthreads();
        f32x4 acc1[M_][4];
        #pragma unroll
        for (int m = 0; m < M_; ++m)
            #pragma unroll
            for (int n = 0; n < 4; ++n) acc1[m][n] = f32x4{0.f, 0.f, 0.f, 0.f};
        #pragma unroll
        for (int kk = 0; kk < 4; ++kk) {
            bf16x8 a[M_], b[4];
            int cb = kk * 64 + lhi * 16;
            #pragma unroll
            for (int m = 0; m < M_; ++m) {
                int row = wr * RW + m * 16 + l15;
                a[m] = *(const bf16x8*)(AsB + row * 256 + (cb ^ X16(row)));
            }
            #pragma unroll
            for (int n = 0; n < 4; ++n) {
                int rb = wc * 64 + n * 16 + l15;
                b[n] = *(const bf16x8*)(BsB + rb * 256 + (cb ^ X16(rb)));
            }
            #pragma unroll
            for (int m = 0; m < M_; ++m)
                #pragma unroll
                for (int n = 0; n < 4; ++n)
                    acc1[m][n] = __builtin_amdgcn_mfma_f32_16x16x32_bf16(a[m], b[n], acc1[m][n], 0, 0, 0);
        }
        #pragma unroll
        for (int m = 0; m < M_; ++m)
            #pragma unroll
            for (int n = 0; n < 4; ++n) {
                int col = c * 128 + wc * 64 + n * 16 + l15;
                float bv = b1[col];
                #pragma unroll
                for (int j = 0; j < 4; ++j) {
                    int row = wr * RW + m * 16 + lhi * 4 + j;
                    float v = gelu_f(acc1[m][n][j] + bv);
                    *(short*)(GLB + row * 1024 + ((col * 2) ^ X16(row))) = f2b(v);
                }
            }
    }

    // ---- phase 2: fc2 ----
    f32x4 acc2[M_][4];
    #pragma unroll
    for (int m = 0; m < M_; ++m)
        #pragma unroll
        for (int n = 0; n < 4; ++n) acc2[m][n] = f32x4{0.f, 0.f, 0.f, 0.f};
    #pragma unroll 1
    for (int kc = 0; kc < 4; ++kc) {
        __syncthreads();
        MSTAGE((const char*)W2t + kc * 256, 1024, BsB, 8);
        asm volatile("s_waitcnt vmcnt(0)" ::: "memory");
        __syncthreads();
        #pragma unroll
        for (int kk = 0; kk < 4; ++kk) {
            bf16x8 a[M_], b[4];
            int cb = kk * 64 + lhi * 16;
            #pragma unroll
            for (int m = 0; m < M_; ++m) {
                int row = wr * RW + m * 16 + l15;
                a[m] = *(const bf16x8*)(GLB + row * 1024 + ((kc * 256 + cb) ^ X16(row)));
            }
            #pragma unroll
            for (int n = 0; n < 4; ++n) {
                int rb = wc * 64 + n * 16 + l15;
                b[n] = *(const bf16x8*)(BsB + rb * 256 + (cb ^ X16(rb)));
            }
            #pragma unroll
            for (int m = 0; m < M_; ++m)
                #pragma unroll
                for (int n = 0; n < 4; ++n)
                    acc2[m][n] = __builtin_amdgcn_mfma_f32_16x16x32_bf16(a[m], b[n], acc2[m][n], 0, 0, 0);
        }
    }

    // ---- final epilogue ----
    #pragma unroll
    for (int m = 0; m < M_; ++m)
        #pragma unroll
        for (int n = 0; n < 4; ++n) {
            int col = wc * 64 + n * 16 + l15;
            float bv = b2[col];
            #pragma unroll
            for (int j = 0; j < 4; ++j) {
                acc2[m][n][j] += bv + acc0[m][n][j];
                if (FIN == 0) {
                    int rr = bm + wr * RW + m * 16 + lhi * 4 + j;
                    if (rr < M) resid[(size_t)rr * 128 + col] = acc2[m][n][j];
                }
            }
        }
    __syncthreads();
    float* sst2 = (float*)GL;
    #pragma unroll
    for (int m = 0; m < M_; ++m)
        #pragma unroll
        for (int j = 0; j < 4; ++j) {
            float ps = 0.f, pq = 0.f;
            #pragma unroll
            for (int n = 0; n < 4; ++n) { float t0 = acc2[m][n][j]; ps += t0; pq += t0 * t0; }
            #pragma unroll
            for (int o = 1; o < 16; o <<= 1) { ps += __shfl_xor(ps, o); pq += __shfl_xor(pq, o); }
            if (l15 == 0) {
                int row = wr * RW + m * 16 + lhi * 4 + j;
                sst2[row * 4 + wc * 2 + 0] = ps;
                sst2[row * 4 + wc * 2 + 1] = pq;
            }
        }
    __syncthreads();
    float pwl[4];
    if (FIN == 2) {
        #pragma unroll
        for (int n = 0; n < 4; ++n) pwl[n] = pwv[wc * 64 + n * 16 + l15];
    }
    float pp[M_][4];
    #pragma unroll
    for (int m = 0; m < M_; ++m)
        #pragma unroll
        for (int j = 0; j < 4; ++j) {
            int row = wr * RW + m * 16 + lhi * 4 + j;
            int rr = bm + row;
            float s0 = sst2[row * 4 + 0] + sst2[row * 4 + 2];
            float q0 = sst2[row * 4 + 1] + sst2[row * 4 + 3];
            float mu = s0 * (1.0f / 128.0f);
            float var = q0 * (1.0f / 128.0f) - mu * mu;
            float rs = rsqrtf(var + EPS_);
            float pacc = 0.f;
            #pragma unroll
            for (int n = 0; n < 4; ++n) {
                int col = wc * 64 + n * 16 + l15;
                float lnv = (acc2[m][n][j] - mu) * rs * lnfw[col] + lnfb[col];
                if (FIN != 2) {
                    if (rr < M) {
                        Lout[(size_t)rr * 128 + col] = f2b(lnv);
                        if (FIN == 1 && (rr % NENC_) == 0)
                            predp[(rr / NENC_) * 128 + col] = lnv;   // cls_out
                    }
                } else {
                    pacc += lnv * pwl[n];
                }
            }
            pp[m][j] = pacc;
        }
    if (FIN == 2) {
        float* sp = (float*)GL + 256;
        #pragma unroll
        for (int m = 0; m < M_; ++m)
            #pragma unroll
            for (int j = 0; j < 4; ++j) {
                float v2 = pp[m][j];
                #pragma unroll
                for (int o = 1; o < 16; o <<= 1) v2 += __shfl_xor(v2, o);
                if (l15 == 0) {
                    int row = wr * RW + m * 16 + lhi * 4 + j;
                    sp[row * 2 + wc] = v2;
                }
            }
        __syncthreads();
        if (tid < 64) {
            float s2 = 0.f;
            if (tid < MT) {
                int gr = bm + tid;
                float pred = sp[tid * 2] + sp[tid * 2 + 1] + pbv[0];
                predp[gr] = pred;
                float dd = pred - xin[gr];
                float msk = (rankp[gr] >= KEEP_) ? 1.0f : 0.0f;
                s2 = dd * dd * msk;
            }
            #pragma unroll
            for (int o = 1; o < 64; o <<= 1) s2 += __shfl_xor(s2, o);
            if (tid == 0) bsumsp[blockIdx.x] = s2;
        }
    }
#undef MSTAGE
}

// ---------------------------------------------------------------------------
// MFMA flash attention, 64-row KV tiles (R13/R16-verified) — used for ENC
// (N=513: even 4/5 tile split, minimal mask waste).
// ---------------------------------------------------------------------------
template<int TAIL>
__global__ __launch_bounds__(256) void attn_mfma_kernel(
    const short* __restrict__ qkv, int N, int rowsTot,
    float* __restrict__ accp, float* __restrict__ mlp) {
    int h = blockIdx.y, b = blockIdx.z;
    int tid = threadIdx.x;
    int lane = tid & 63, wid = tid >> 6;
    int l15 = lane & 15, lhi = lane >> 4;
    __shared__ __align__(16) short smem[2][2048];

    const short* base = qkv + (size_t)b * N * 384;
    int qt = blockIdx.x >> 1;
    int half = blockIdx.x & 1;

    int q0w = qt * 64 + wid * 16;
    int qi = q0w + l15;
    int qc = qi < N ? qi : N - 1;
    bf16x8 qf = *(const bf16x8*)(base + (size_t)qc * 384 + h * 16 + (lhi & 1) * 8);
    if (lhi >= 2) qf = bf16x8{0, 0, 0, 0, 0, 0, 0, 0};

    bool isK = (wid < 2);
    int r64 = ((wid & 1) << 5) | (lane >> 1);
    int hb = lane & 1;
    int t_ = r64 >> 4, rr = r64 & 15;
    int gp = ((t_ >> 1) << 5) | ((rr >> 2) << 3) | ((t_ & 1) << 2) | (rr & 3);
    int vp = r64 ^ ((r64 >> 3) & 3);           // V row perm (involution)
    int grow = isK ? gp : vp;
    int soff = (isK ? 128 : 256) + h * 16 + hb * 8;
    int ldsWaveOff = (isK ? 0 : 2048) + ((wid & 1) << 10);

    f32x4 acc = f32x4{0.f, 0.f, 0.f, 0.f};
    float mrun = -1e30f, lrun = 0.f;
    int nktT = (N + 63) >> 6;
    int lo = half * (nktT >> 1);
    int hi = half ? nktT : (nktT >> 1);

#define STAGE(KT, BUFI) do {                                                        \
        int row_ = (KT) * 64 + grow;                                                \
        row_ = row_ < N ? row_ : N - 1;                                             \
        __builtin_amdgcn_global_load_lds(                                           \
            (const __attribute__((address_space(1))) void*)(base + (size_t)row_ * 384 + soff), \
            (__attribute__((address_space(3))) void*)((char*)&smem[BUFI][0] + ldsWaveOff), 16, 0, 0); \
    } while (0)

    STAGE(lo, 0);
    for (int kt = lo; kt < hi; ++kt) {
        int bf = (kt - lo) & 1;
        if (kt + 1 < hi) {
            STAGE(kt + 1, bf ^ 1);
            asm volatile("s_waitcnt vmcnt(1)" ::: "memory");
        } else {
            asm volatile("s_waitcnt vmcnt(0)" ::: "memory");
        }
        __builtin_amdgcn_s_barrier();
        asm volatile("" ::: "memory");

        const short* kb = smem[bf];
        const short* vb = kb + 1024;

        f32x4 s4[4];
        __builtin_amdgcn_s_setprio(1);
        #pragma unroll
        for (int t = 0; t < 4; ++t) {
            bf16x8 kf = *(const bf16x8*)(kb + (t * 16 + l15) * 16 + (lhi & 1) * 8);
            s4[t] = __builtin_amdgcn_mfma_f32_16x16x32_bf16(kf, qf, f32x4{0.f, 0.f, 0.f, 0.f}, 0, 0, 0);
        }
        __builtin_amdgcn_s_setprio(0);

        int kv0 = kt * 64;
        float pvv[4][4];
        float mx = -1e30f;
        #pragma unroll
        for (int t = 0; t < 4; ++t)
            #pragma unroll
            for (int r = 0; r < 4; ++r) {
                float v = s4[t][r];
                if (TAIL) {
                    if (kv0 + 64 > N) {
                        int kvg = ((t >> 1) << 5) | (lhi << 3) | ((t & 1) << 2) | r;
                        if (kv0 + kvg >= N) v = -1e30f;
                    }
                }
                pvv[t][r] = v;
                mx = fmaxf(mx, v);
            }
        mx = fmaxf(mx, __shfl_xor(mx, 16));
        mx = fmaxf(mx, __shfl_xor(mx, 32));
        if (!__all(mx - mrun <= 8.0f)) {            // defer-max (T13)
            float mnew = fmaxf(mrun, mx);
            float fr = fexp2(mrun - mnew);
            mrun = mnew;
            lrun *= fr;
            acc[0] *= fr; acc[1] *= fr; acc[2] *= fr; acc[3] *= fr;
        }
        float psum = 0.f;
        #pragma unroll
        for (int t = 0; t < 4; ++t)
            #pragma unroll
            for (int r = 0; r < 4; ++r) {
                float pp = fexp2(pvv[t][r] - mrun);
                pvv[t][r] = pp;
                psum += pp;
            }
        lrun += psum;

        union { bf16x8 v8; unsigned u[4]; } pa0u, pa1u;
        pa0u.u[0] = cvtpk(pvv[0][0], pvv[0][1]);
        pa0u.u[1] = cvtpk(pvv[0][2], pvv[0][3]);
        pa0u.u[2] = cvtpk(pvv[1][0], pvv[1][1]);
        pa0u.u[3] = cvtpk(pvv[1][2], pvv[1][3]);
        pa1u.u[0] = cvtpk(pvv[2][0], pvv[2][1]);
        pa1u.u[1] = cvtpk(pvv[2][2], pvv[2][3]);
        pa1u.u[2] = cvtpk(pvv[3][0], pvv[3][1]);
        pa1u.u[3] = cvtpk(pvv[3][2], pvv[3][3]);

        bf16x8 vf0, vf1;
        #pragma unroll
        for (int i2 = 0; i2 < 8; ++i2) {
            int pr = lhi * 8 + (i2 ^ lhi);
            vf0[i2] = vb[pr * 16 + l15];
            vf1[i2] = vb[(32 + pr) * 16 + l15];
        }
        __builtin_amdgcn_s_setprio(1);
        acc = __builtin_amdgcn_mfma_f32_16x16x32_bf16(vf0, pa0u.v8, acc, 0, 0, 0);
        acc = __builtin_amdgcn_mfma_f32_16x16x32_bf16(vf1, pa1u.v8, acc, 0, 0, 0);
        __builtin_amdgcn_s_setprio(0);

        asm volatile("s_waitcnt lgkmcnt(0)" ::: "memory");
        __builtin_amdgcn_s_barrier();
        asm volatile("" ::: "memory");
    }
#undef STAGE

    lrun += __shfl_xor(lrun, 16);
    lrun += __shfl_xor(lrun, 32);
    if (qi < N) {
        size_t row = (size_t)b * N + qi;
        *(f32x4*)(accp + ((size_t)half * rowsTot + row) * 128 + h * 16 + lhi * 4) = acc;
        if (lhi == 0) {
            float* mlq = mlp + ((size_t)half * rowsTot + row) * 16 + h * 2;
            mlq[0] = mrun;
            mlq[1] = lrun;
        }
    }
}

// ---------------------------------------------------------------------------
// MFMA flash attention, 128-row staging processed as 2 serialized 64-row
// subtiles (R22-verified) — used for DEC (N=2048, divisible by 128).
// Halves barriers/vmcnt/loop overhead while keeping VGPR at the 64-tile level.
// ---------------------------------------------------------------------------
__global__ __launch_bounds__(256) void attn_mfma128_kernel(
    const short* __restrict__ qkv, int N, int rowsTot,
    float* __restrict__ accp, float* __restrict__ mlp) {
    int h = blockIdx.y, b = blockIdx.z;
    int tid = threadIdx.x;
    int lane = tid & 63, wid = tid >> 6;
    int l15 = lane & 15, lhi = lane >> 4;
    __shared__ __align__(16) short smem[2][4096];   // per buf: K[128][16] | V[128][16]

    const short* base = qkv + (size_t)b * N * 384;
    int qt = blockIdx.x >> 1;
    int half = blockIdx.x & 1;

    int q0w = qt * 64 + wid * 16;
    int qi = q0w + l15;
    bf16x8 qf = *(const bf16x8*)(base + (size_t)qi * 384 + h * 16 + (lhi & 1) * 8);
    if (lhi >= 2) qf = bf16x8{0, 0, 0, 0, 0, 0, 0, 0};

    bool isK = (wid < 2);
    int r64 = ((wid & 1) << 5) | (lane >> 1);
    int hb = lane & 1;
    int t_ = r64 >> 4, rr = r64 & 15;
    int gp = ((t_ >> 1) << 5) | ((rr >> 2) << 3) | ((t_ & 1) << 2) | (rr & 3);
    int vp = r64 ^ ((r64 >> 3) & 3);           // V row perm (involution)
    int grow = isK ? gp : vp;
    int soff = (isK ? 128 : 256) + h * 16 + hb * 8;
    int ldsWaveOff = (isK ? 0 : 4096) + ((wid & 1) << 10);   // bytes within buf

    f32x4 acc = f32x4{0.f, 0.f, 0.f, 0.f};
    float mrun = -1e30f, lrun = 0.f;
    int nktT = N >> 7;
    int lo = half * (nktT >> 1);
    int hi = half ? nktT : (nktT >> 1);

#define STAGE(KT, BUFI) do {                                                        \
        int ra_ = (KT) * 128 + grow;                                                \
        int rb_ = ra_ + 64;                                                         \
        __builtin_amdgcn_global_load_lds(                                           \
            (const __attribute__((address_space(1))) void*)(base + (size_t)ra_ * 384 + soff), \
            (__attribute__((address_space(3))) void*)((char*)&smem[BUFI][0] + ldsWaveOff), 16, 0, 0); \
        __builtin_amdgcn_global_load_lds(                                           \
            (const __attribute__((address_space(1))) void*)(base + (size_t)rb_ * 384 + soff), \
            (__attribute__((address_space(3))) void*)((char*)&smem[BUFI][0] + ldsWaveOff + 2048), 16, 0, 0); \
    } while (0)

    STAGE(lo, 0);
    for (int kt = lo; kt < hi; ++kt) {
        int bf = (kt - lo) & 1;
        if (kt + 1 < hi) {
            STAGE(kt + 1, bf ^ 1);
            asm volatile("s_waitcnt vmcnt(2)" ::: "memory");
        } else {
            asm volatile("s_waitcnt vmcnt(0)" ::: "memory");
        }
        __builtin_amdgcn_s_barrier();
        asm volatile("" ::: "memory");

        const short* kb = smem[bf];          // K rows 0..127 (subtile s at +s*1024)
        const short* vb = kb + 2048;         // V rows 0..127 (subtile s at +s*1024)

        #pragma unroll
        for (int s = 0; s < 2; ++s) {
            const short* kbs = kb + s * 1024;
            const short* vbs = vb + s * 1024;

            f32x4 s4[4];
            __builtin_amdgcn_s_setprio(1);
            #pragma unroll
            for (int t = 0; t < 4; ++t) {
                bf16x8 kf = *(const bf16x8*)(kbs + (t * 16 + l15) * 16 + (lhi & 1) * 8);
                s4[t] = __builtin_amdgcn_mfma_f32_16x16x32_bf16(kf, qf, f32x4{0.f, 0.f, 0.f, 0.f}, 0, 0, 0);
            }
            __builtin_amdgcn_s_setprio(0);

            float pvv[4][4];
            float mx = -1e30f;
            #pragma unroll
            for (int t = 0; t < 4; ++t)
                #pragma unroll
                for (int r = 0; r < 4; ++r) {
                    float v = s4[t][r];
                    pvv[t][r] = v;
                    mx = fmaxf(mx, v);
                }
            mx = fmaxf(mx, __shfl_xor(mx, 16));
            mx = fmaxf(mx, __shfl_xor(mx, 32));
            if (!__all(mx - mrun <= 8.0f)) {            // defer-max (T13)
                float mnew = fmaxf(mrun, mx);
                float fr = fexp2(mrun - mnew);
                mrun = mnew;
                lrun *= fr;
                acc[0] *= fr; acc[1] *= fr; acc[2] *= fr; acc[3] *= fr;
            }
            float psum = 0.f;
            #pragma unroll
            for (int t = 0; t < 4; ++t)
                #pragma unroll
                for (int r = 0; r < 4; ++r) {
                    float pp = fexp2(pvv[t][r] - mrun);
                    pvv[t][r] = pp;
                    psum += pp;
                }
            lrun += psum;

            union { bf16x8 v8; unsigned u[4]; } pa0u, pa1u;
            pa0u.u[0] = cvtpk(pvv[0][0], pvv[0][1]);
            pa0u.u[1] = cvtpk(pvv[0][2], pvv[0][3]);
            pa0u.u[2] = cvtpk(pvv[1][0], pvv[1][1]);
            pa0u.u[3] = cvtpk(pvv[1][2], pvv[1][3]);
            pa1u.u[0] = cvtpk(pvv[2][0], pvv[2][1]);
            pa1u.u[1] = cvtpk(pvv[2][2], pvv[2][3]);
            pa1u.u[2] = cvtpk(pvv[3][0], pvv[3][1]);
            pa1u.u[3] = cvtpk(pvv[3][2], pvv[3][3]);

            bf16x8 vf0, vf1;
            #pragma unroll
            for (int i2 = 0; i2 < 8; ++i2) {
                int pr = lhi * 8 + (i2 ^ lhi);
                vf0[i2] = vbs[pr * 16 + l15];
                vf1[i2] = vbs[(32 + pr) * 16 + l15];
            }
            __builtin_amdgcn_s_setprio(1);
            acc = __builtin_amdgcn_mfma_f32_16x16x32_bf16(vf0, pa0u.v8, acc, 0, 0, 0);
            acc = __builtin_amdgcn_mfma_f32_16x16x32_bf16(vf1, pa1u.v8, acc, 0, 0, 0);
            __builtin_amdgcn_s_setprio(0);
        }

        asm volatile("s_waitcnt lgkmcnt(0)" ::: "memory");
        __builtin_amdgcn_s_barrier();
        asm volatile("" ::: "memory");
    }
#undef STAGE

    lrun += __shfl_xor(lrun, 16);
    lrun += __shfl_xor(lrun, 32);
    {
        size_t row = (size_t)b * N + qi;
        *(f32x4*)(accp + ((size_t)half * rowsTot + row) * 128 + h * 16 + lhi * 4) = acc;
        if (lhi == 0) {
            float* mlq = mlp + ((size_t)half * rowsTot + row) * 16 + h * 2;
            mlq[0] = mrun;
            mlq[1] = lrun;
        }
    }
}

// ---------------------------------------------------------------------------
__global__ void loss_fin_kernel(const float* __restrict__ bs, float* __restrict__ out0) {
    int t = threadIdx.x;   // 64
    float s = bs[t] + bs[t + 64] + bs[t + 128] + bs[t + 192];
    #pragma unroll
    for (int o = 1; o < 64; o <<= 1) s += __shfl_xor(s, o);
    if (t == 0) out0[0] = s * (1.0f / 6144.0f);
}

// ---------------------------------------------------------------------------
extern "C" void kernel_launch(void* const* d_in, const int* in_sizes, int n_in,
                              void* d_out, int out_size, void* d_ws, size_t ws_size,
                              hipStream_t stream) {
    const float* x     = (const float*)d_in[0];
    const float* noise = (const float*)d_in[1];
    const float* pos   = (const float*)d_in[2];
    const float* cls   = (const float*)d_in[3];
    const float* eew   = (const float*)d_in[4];
    const float* eeb   = (const float*)d_in[5];
    const float* nw    = (const float*)d_in[6];
    const float* nb    = (const float*)d_in[7];
    const float* dew   = (const float*)d_in[8];
    const float* deb   = (const float*)d_in[9];
    const float* mtok  = (const float*)d_in[10];
    const float* dnw   = (const float*)d_in[11];
    const float* dnb   = (const float*)d_in[12];
    const float* pw    = (const float*)d_in[13];
    const float* pb    = (const float*)d_in[14];
    const float* eln1w = (const float*)d_in[15];
    const float* eln1b = (const float*)d_in[16];
    const float* eqkvw = (const float*)d_in[17];
    const float* eqkvb = (const float*)d_in[18];
    const float* eprjw = (const float*)d_in[19];
    const float* eprjb = (const float*)d_in[20];
    const float* eln2w = (const float*)d_in[21];
    const float* eln2b = (const float*)d_in[22];
    const float* ef1w  = (const float*)d_in[23];
    const float* ef1b  = (const float*)d_in[24];
    const float* ef2w  = (const float*)d_in[25];
    const float* ef2b  = (const float*)d_in[26];
    const float* dln1w = (const float*)d_in[27];
    const float* dln1b = (const float*)d_in[28];
    const float* dqkvw = (const float*)d_in[29];
    const float* dqkvb = (const float*)d_in[30];
    const float* dprjw = (const float*)d_in[31];
    const float* dprjb = (const float*)d_in[32];
    const float* dln2w = (const float*)d_in[33];
    const float* dln2b = (const float*)d_in[34];
    const float* df1w  = (const float*)d_in[35];
    const float* df1b  = (const float*)d_in[36];
    const float* df2w  = (const float*)d_in[37];
    const float* df2b  = (const float*)d_in[38];

    char* ws = (char*)d_ws;
    int*   rank    = (int*)(ws + 0);              // 32768
    int*   keep    = (int*)(ws + 32768);          // 8192
    float* bsums   = (float*)(ws + 40960);        // 8192
    float* enc_x   = (float*)(ws + 49152);        // 1050624
    float* decx    = (float*)(ws + 1099776);      // 4194304
    short* qkvb16  = (short*)(ws + 5294080);      // 6291456
    short* attnb16 = (short*)(ws + 11585536);     // 2097152 (unused now)
    short* lnb16   = (short*)(ws + 13682688);     // 2097152
    short* scr     = (short*)(ws + 15779840);     // 8388608  (accp partials)
    short* latb16  = (short*)(ws + 24168448);     // 557056
    float* demb    = (float*)(ws + 24725504);     // 1050624
    short* eqkvT   = (short*)(ws + 25776128);     // 589824
    short* eprjT   = (short*)(ws + 26365952);     // 196608
    short* ef1T    = (short*)(ws + 26562560);     // 786432
    short* ef2T    = (short*)(ws + 27348992);     // 786432
    short* dqkvT   = (short*)(ws + 28135424);     // 196608
    short* dprjT   = (short*)(ws + 28332032);     // 65536
    short* df1T    = (short*)(ws + 28397568);     // 262144
    short* df2T    = (short*)(ws + 28659712);     // 262144
    short* dembT   = (short*)(ws + 28921856);     // 32768
    float* mlp     = (float*)(ws + 28954624);     // 1048576 (2*8192*16*4) own region

    float* accp = (float*)scr;

    float* outp = (float*)d_out;
    float* pred_out = outp + 1;
    float* mask_out = outp + 1 + B_ * G_;
    float* cls_out  = outp + 1 + 2 * B_ * G_;

    prep_kernel<<<dim3(16, 16, 33), 256, 0, stream>>>(
        eqkvw, eprjw, ef1w, ef2w, dqkvw, dprjw, df1w, df2w, dew,
        eqkvT, eprjT, ef1T, ef2T, dqkvT, dprjT, df1T, df2T, dembT);

    rank_kernel<<<dim3(G_ / 256, B_), 1024, 0, stream>>>(noise, rank, keep, mask_out);
    embed_ln_kernel<<<dim3(NENC_, B_), 128, 0, stream>>>(x, pos, cls, eew, eeb, keep,
                                                         eln1w, eln1b, enc_x, lnb16);

    const int Menc = B_ * NENC_;                 // 2052
    const int gqE = (Menc + 31) / 32;            // 65  (BM=32)
    const int mbE = (Menc + 31) / 32;            // 65  (MT=32)
    const int nqtE = (NENC_ + 63) / 64;          // 9
    for (int L = 0; L < 6; ++L) {
        gemm_mfma_kernel<3, 32><<<dim3(gqE, 3), 256, 0, stream>>>(lnb16, eqkvT + (size_t)L * 384 * 128,
            eqkvb + L * 384, qkvb16, Menc, 128, 384);
        attn_mfma_kernel<1><<<dim3(2 * nqtE, NH_, B_), 256, 0, stream>>>(
            qkvb16, NENC_, Menc, accp, mlp);
        if (L < 5) {
            mega_mlp_kernel<0, 32><<<mbE, 256, 0, stream>>>(
                accp, mlp, Menc, eprjT + (size_t)L * 128 * 128, eprjb + L * D_, enc_x,
                ef1T + (size_t)L * 512 * 128, ef1b + L * HID_,
                ef2T + (size_t)L * 128 * 512, ef2b + L * D_,
                eln2w + L * D_, eln2b + L * D_,
                eln1w + (L + 1) * D_, eln1b + (L + 1) * D_, lnb16,
                nullptr, nullptr, nullptr, nullptr, nullptr, nullptr, Menc);
        } else {
            mega_mlp_kernel<1, 32><<<mbE, 256, 0, stream>>>(
                accp, mlp, Menc, eprjT + (size_t)L * 128 * 128, eprjb + L * D_, enc_x,
                ef1T + (size_t)L * 512 * 128, ef1b + L * HID_,
                ef2T + (size_t)L * 128 * 512, ef2b + L * D_,
                eln2w + L * D_, eln2b + L * D_,
                nw, nb, latb16,
                nullptr, nullptr, nullptr, nullptr, cls_out, nullptr, Menc);
        }
    }

    gemm_mfma_kernel<0, 32><<<dim3(gqE, 1), 256, 0, stream>>>(latb16, dembT, deb, demb, Menc, 128, 128);
    decbuild_ln_kernel<<<dim3(G_, B_), 128, 0, stream>>>(demb, mtok, pos, rank,
                                                         dln1w, dln1b, decx, lnb16);

    const int Mdec = B_ * G_;                    // 8192
    const int gqD = Mdec / 32;                   // 256 (BM=32)
    const int mbD = Mdec / 32;                   // 256 (MT=32)
    for (int L = 0; L < 2; ++L) {
        gemm_mfma_kernel<3, 32><<<dim3(gqD, 3), 256, 0, stream>>>(lnb16, dqkvT + (size_t)L * 384 * 128,
            dqkvb + L * 384, qkvb16, Mdec, 128, 384);
        attn_mfma128_kernel<<<dim3(2 * (G_ / 64), NH_, B_), 256, 0, stream>>>(
            qkvb16, G_, Mdec, accp, mlp);
        if (L == 0) {
            mega_mlp_kernel<0, 32><<<mbD, 256, 0, stream>>>(
                accp, mlp, Mdec, dprjT + (size_t)L * 128 * 128, dprjb + L * D_, decx,
                df1T + (size_t)L * 512 * 128, df1b + L * HID_,
                df2T + (size_t)L * 128 * 512, df2b + L * D_,
                dln2w + L * D_, dln2b + L * D_,
                dln1w + D_, dln1b + D_, lnb16,
                nullptr, nullptr, nullptr, nullptr, nullptr, nullptr, Mdec);
        } else {
            mega_mlp_kernel<2, 32><<<mbD, 256, 0, stream>>>(
                accp, mlp, Mdec, dprjT + (size_t)L * 128 * 128, dprjb + L * D_, decx,
                df1T + (size_t)L * 512 * 128, df1b + L * HID_,
                df2T + (size_t)L * 128 * 512, df2b + L * D_,
                dln2w + L * D_, dln2b + L * D_,
                dnw, dnb, nullptr,
                pw, pb, x, rank, pred_out, bsums, Mdec);
        }
    }

    loss_fin_kernel<<<1, 64, 0, stream>>>(bsums, outp);
}